// Round 6
// baseline (1275.638 us; speedup 1.0000x reference)
//
#include <hip/hip_runtime.h>
#include <math.h>

#define NB 512
#define NT 64
#define ND 512
#define NH 256
#define NA 256
#define NC 96
#define NSTEPS 26
#define NGRU 1152   // 1024 interleaved gru rows + 96 fc + 32 pad
#define KGRU 768    // [ctx(512) | h(256)]

typedef __attribute__((ext_vector_type(8))) short short8;
typedef __attribute__((ext_vector_type(4))) float f32x4;

static __device__ __forceinline__ unsigned short f2bf(float f) {
    unsigned int u = __float_as_uint(f);
    unsigned int r = (u + 0x7FFFu + ((u >> 16) & 1u)) >> 16;
    return (unsigned short)r;
}
static __device__ __forceinline__ float bf2f(unsigned short u) {
    return __uint_as_float(((unsigned int)u) << 16);
}

// ---------------------------------------------------------------------------
// Prep. Wp [1152 x 768] bf16, rows interleaved (4j+g), K = [ctx | h]:
//   g=0 r : [Wih_r[:,256:768] | Whh_r]
//   g=1 z : [Wih_z[:,256:768] | Whh_z]
//   g=2 ni: [Wih_n[:,256:768] | 0    ]
//   g=3 nh: [0                | Whh_n]
//   rows 1024-1119 FC: [0 | Wfc];  1120-1151 pad.
// Also Wxbf, Wsbf, WfcT. grid 3456 x 256.
// ---------------------------------------------------------------------------
__global__ __launch_bounds__(256) void k_prep(
    const float* __restrict__ Wx, const float* __restrict__ Ws,
    const float* __restrict__ Wfc, const float* __restrict__ Wih,
    const float* __restrict__ Whh,
    unsigned short* __restrict__ Wxbf, unsigned short* __restrict__ Wsbf,
    unsigned short* __restrict__ WfcT, unsigned short* __restrict__ Wp)
{
    const int idx = blockIdx.x * 256 + threadIdx.x;
    if (idx < NGRU * KGRU) {
        const int n = idx / KGRU, k = idx - n * KGRU;
        float val = 0.f;
        if (n < 1024) {
            const int j = n >> 2, g = n & 3;
            if (k < 512) {
                if (g == 0)      val = Wih[j * 768 + 256 + k];
                else if (g == 1) val = Wih[(256 + j) * 768 + 256 + k];
                else if (g == 2) val = Wih[(512 + j) * 768 + 256 + k];
            } else {
                const int kh = k - 512;
                if (g == 0)      val = Whh[j * 256 + kh];
                else if (g == 1) val = Whh[(256 + j) * 256 + kh];
                else if (g == 3) val = Whh[(512 + j) * 256 + kh];
            }
        } else if (n < 1120) {
            if (k >= 512) val = Wfc[(n - 1024) * 256 + (k - 512)];
        }
        Wp[idx] = f2bf(val);
    }
    if (idx < 131072) Wxbf[idx] = f2bf(Wx[idx]);
    if (idx < 65536)  Wsbf[idx] = f2bf(Ws[idx]);        // row-major [j][k]
    if (idx < 24576) {
        const int k = idx / 96, c = idx % 96;
        WfcT[idx] = f2bf(Wfc[c * 256 + k]);             // WfcT[k][c]
    }
}

// ---------------------------------------------------------------------------
// embProj: P[y][n] = bias(n) + sum_{k<256} emb[y][k] * Wemb(n,k), fp32.
// bias folded in (incl. bfc for FC rows). grid (97, 5) x 256.
// ---------------------------------------------------------------------------
__global__ __launch_bounds__(256) void k_prep2(
    const float* __restrict__ emb, const float* __restrict__ Wih,
    const float* __restrict__ bih, const float* __restrict__ bhh,
    const float* __restrict__ bfc, float* __restrict__ P)
{
    const int y = blockIdx.x;
    const int n = blockIdx.y * 256 + threadIdx.x;
    __shared__ float embS[256];
    embS[threadIdx.x] = emb[y * 256 + threadIdx.x];
    __syncthreads();
    if (n >= NGRU) return;

    float bias = 0.f;
    const float* src = nullptr;
    if (n < 1024) {
        const int j = n >> 2, g = n & 3;
        if (g == 0)      { bias = bih[j] + bhh[j];             src = Wih + (size_t)j * 768; }
        else if (g == 1) { bias = bih[256 + j] + bhh[256 + j]; src = Wih + (size_t)(256 + j) * 768; }
        else if (g == 2) { bias = bih[512 + j];                src = Wih + (size_t)(512 + j) * 768; }
        else             { bias = bhh[512 + j]; }
    } else if (n < 1120) {
        bias = bfc[n - 1024];
    }
    float sp = bias;
    if (src) {
#pragma unroll 8
        for (int k = 0; k < 256; ++k) sp = fmaf(embS[k], src[k], sp);
    }
    P[(size_t)y * NGRU + n] = sp;
}

// img fp32 -> bf16. grid 8192 x 256.
__global__ __launch_bounds__(256) void k_convert(
    const float* __restrict__ img, unsigned short* __restrict__ imgbf)
{
    const int idx = (blockIdx.x * 256 + threadIdx.x) * 8;
    const float4 v0 = *(const float4*)(img + idx);
    const float4 v1 = *(const float4*)(img + idx + 4);
    short8 o;
    o[0] = (short)f2bf(v0.x); o[1] = (short)f2bf(v0.y);
    o[2] = (short)f2bf(v0.z); o[3] = (short)f2bf(v0.w);
    o[4] = (short)f2bf(v1.x); o[5] = (short)f2bf(v1.y);
    o[6] = (short)f2bf(v1.z); o[7] = (short)f2bf(v1.w);
    *(short8*)(imgbf + idx) = o;
}

// ---------------------------------------------------------------------------
// xProj = img @ Wx.T + bx -> bf16. M=32768 N=256 K=512.
// ---------------------------------------------------------------------------
__global__ __launch_bounds__(256) void k_xproj(
    const float* __restrict__ img, const unsigned short* __restrict__ imgbf,
    int use_bf, const unsigned short* __restrict__ Wxbf,
    const float* __restrict__ bx, unsigned short* __restrict__ xProjbf)
{
    __shared__ unsigned short As[64][40];
    __shared__ unsigned short Bs[64][40];

    const int tid = threadIdx.x;
    const int lane = tid & 63;
    const int w = tid >> 6;
    const int l15 = lane & 15;
    const int q = lane >> 4;
    const int bm = blockIdx.x * 64;
    const int bn = blockIdx.y * 64;
    const int srow = tid >> 2;
    const int sc0 = (tid & 3) * 8;

    f32x4 acc[4];
#pragma unroll
    for (int i = 0; i < 4; ++i) acc[i] = (f32x4){0.f, 0.f, 0.f, 0.f};

    for (int k0 = 0; k0 < ND; k0 += 32) {
        if (use_bf) {
            *(short8*)&As[srow][sc0] =
                *(const short8*)(imgbf + (size_t)(bm + srow) * ND + k0 + sc0);
        } else {
            const float* ap = img + (size_t)(bm + srow) * ND + k0 + sc0;
            const float4 v0 = *(const float4*)ap;
            const float4 v1 = *(const float4*)(ap + 4);
            short8 av;
            av[0] = (short)f2bf(v0.x); av[1] = (short)f2bf(v0.y);
            av[2] = (short)f2bf(v0.z); av[3] = (short)f2bf(v0.w);
            av[4] = (short)f2bf(v1.x); av[5] = (short)f2bf(v1.y);
            av[6] = (short)f2bf(v1.z); av[7] = (short)f2bf(v1.w);
            *(short8*)&As[srow][sc0] = av;
        }
        *(short8*)&Bs[srow][sc0] =
            *(const short8*)(Wxbf + (size_t)(bn + srow) * ND + k0 + sc0);
        __syncthreads();

        const short8 bf = *(const short8*)&Bs[w * 16 + l15][q * 8];
#pragma unroll
        for (int mt = 0; mt < 4; ++mt) {
            const short8 af = *(const short8*)&As[mt * 16 + l15][q * 8];
            acc[mt] = __builtin_amdgcn_mfma_f32_16x16x32_bf16(af, bf, acc[mt], 0, 0, 0);
        }
        __syncthreads();
    }

#pragma unroll
    for (int mt = 0; mt < 4; ++mt) {
        const int col = bn + w * 16 + l15;
        const float bxv = bx[col];
#pragma unroll
        for (int r = 0; r < 4; ++r) {
            const int row = bm + mt * 16 + q * 4 + r;
            xProjbf[(size_t)row * NA + col] = f2bf(acc[mt][r] + bxv);
        }
    }
}

// ---------------------------------------------------------------------------
// GRU GEMM + gate epilogue.  Ain [512,768] = [ctx | h] bf16.
// pre[n] = Ain @ Wp[n].T + P[y_s[b]][n]  (P holds emb-proj + bias).
// gru tiles (by<16): gate -> h (f32) + Aout h-slot (bf16).
// FC tiles (by>=16): out[b, s-1, c] when s>=1.
// tile 64x64, BK=64, grid (8,18), 256 threads.
// ---------------------------------------------------------------------------
__global__ __launch_bounds__(256) void k_gru(
    const unsigned short* __restrict__ Ain, unsigned short* __restrict__ Aout,
    const unsigned short* __restrict__ Wp, const float* __restrict__ P,
    const int* __restrict__ label, float* __restrict__ h,
    float* __restrict__ out, int s)
{
    __shared__ __align__(16) unsigned char smem[64 * 72 * 2 * 2];   // As+Bs; CS aliases
    unsigned short (*As)[72] = (unsigned short(*)[72])smem;
    unsigned short (*Bs)[72] = (unsigned short(*)[72])(smem + 64 * 72 * 2);
    float (*CS)[65] = (float(*)[65])smem;                            // 16640 B <= 18432
    __shared__ int yS[64];

    const int tid = threadIdx.x;
    const int lane = tid & 63;
    const int w = tid >> 6;
    const int l15 = lane & 15;
    const int q = lane >> 4;
    const int bm = blockIdx.x * 64;
    const int bn = blockIdx.y * 64;

    if (tid < 64)
        yS[tid] = (s == 0) ? 0 : label[(bm + tid) * NSTEPS + s];

    f32x4 acc[4];
#pragma unroll
    for (int i = 0; i < 4; ++i) acc[i] = (f32x4){0.f, 0.f, 0.f, 0.f};

    for (int k0 = 0; k0 < KGRU; k0 += 64) {
#pragma unroll
        for (int rep = 0; rep < 2; ++rep) {
            const int c = tid + rep * 256;
            const int row = c >> 3, col8 = (c & 7) * 8;
            *(short8*)&As[row][col8] =
                *(const short8*)(Ain + (size_t)(bm + row) * KGRU + k0 + col8);
            *(short8*)&Bs[row][col8] =
                *(const short8*)(Wp + (size_t)(bn + row) * KGRU + k0 + col8);
        }
        __syncthreads();
#pragma unroll
        for (int kk = 0; kk < 64; kk += 32) {
            const short8 bf = *(const short8*)&Bs[w * 16 + l15][kk + q * 8];
#pragma unroll
            for (int mt = 0; mt < 4; ++mt) {
                const short8 af = *(const short8*)&As[mt * 16 + l15][kk + q * 8];
                acc[mt] = __builtin_amdgcn_mfma_f32_16x16x32_bf16(af, bf, acc[mt], 0, 0, 0);
            }
        }
        __syncthreads();
    }

    const int col = bn + w * 16 + l15;
    if (blockIdx.y < 16) {
        // gru tile: biased pre-activations to LDS (CS aliases As/Bs), then gate
#pragma unroll
        for (int mt = 0; mt < 4; ++mt)
#pragma unroll
            for (int r = 0; r < 4; ++r) {
                const int row = mt * 16 + q * 4 + r;
                CS[row][w * 16 + l15] = acc[mt][r] + P[(size_t)yS[row] * NGRU + col];
            }
        __syncthreads();
#pragma unroll
        for (int it = 0; it < 4; ++it) {
            const int u = tid + 256 * it;          // 0..1023
            const int row = u >> 4;                // 0..63
            const int jl = u & 15;
            const float r_pre = CS[row][4 * jl + 0];
            const float z_pre = CS[row][4 * jl + 1];
            const float ni    = CS[row][4 * jl + 2];
            const float nh    = CS[row][4 * jl + 3];
            const float r = 1.f / (1.f + expf(-r_pre));
            const float z = 1.f / (1.f + expf(-z_pre));
            const float n = tanhf(fmaf(r, nh, ni));
            const int b = bm + row;
            const int j = (bn >> 2) + jl;
            const float hp = h[b * NH + j];
            const float hn = (1.f - z) * n + z * hp;
            h[b * NH + j] = hn;
            Aout[(size_t)b * KGRU + 512 + j] = f2bf(hn);
        }
    } else {
        if (s >= 1) {
            const int c = col - 1024;
            if (c < NC) {
#pragma unroll
                for (int mt = 0; mt < 4; ++mt)
#pragma unroll
                    for (int r = 0; r < 4; ++r) {
                        const int row = mt * 16 + q * 4 + r;
                        out[((size_t)(bm + row) * NSTEPS + (s - 1)) * NC + c] =
                            acc[mt][r] + P[(size_t)yS[row] * NGRU + col];
                    }
            }
        }
    }
}

// ---------------------------------------------------------------------------
// Attention step: sProj + scores + softmax + ctx -> Aout[:,0:512].
// 512 threads, grid 512.  step==-1: init (h=0, zero h-slot).
// ---------------------------------------------------------------------------
__global__ __launch_bounds__(512) void k_step(
    float* __restrict__ h, unsigned short* __restrict__ Aout,
    const unsigned short* __restrict__ Wsbf, const float* __restrict__ bs,
    const unsigned short* __restrict__ imgbf, const float* __restrict__ imgf,
    int use_bf, const unsigned short* __restrict__ xProjbf,
    const float* __restrict__ Ww, const float* __restrict__ bw, int step)
{
    const int b = blockIdx.x;
    const int tid = threadIdx.x;
    const int lane = tid & 63;
    const int w = tid >> 6;

    __shared__ float hS[NH];
    __shared__ float wwS[NA];
    __shared__ float bsS[NA];
    __shared__ float spS[2][NA];
    __shared__ float vS[NT];
    __shared__ float alphaS[NT];
    __shared__ float ctxS[8][512];

    if (tid < 256) {
        wwS[tid] = Ww[tid];
        bsS[tid] = bs[tid];
        if (step >= 0) {
            hS[tid] = h[b * NH + tid];
        } else {
            hS[tid] = 0.f;
            h[b * NH + tid] = 0.f;
            Aout[(size_t)b * KGRU + 512 + tid] = 0;   // bf16(0)
        }
    }
    __syncthreads();

    // ---- sProj split-K ----
    {
        const int j = tid & 255, half = tid >> 8;
        float sp = 0.f;
        if (step >= 0) {
            const unsigned short* wr = Wsbf + (size_t)j * NH + half * 128;
#pragma unroll
            for (int kk = 0; kk < 16; ++kk) {
                const short8 wv = *(const short8*)(wr + kk * 8);
#pragma unroll
                for (int i = 0; i < 8; ++i)
                    sp = fmaf(hS[half * 128 + kk * 8 + i],
                              bf2f((unsigned short)wv[i]), sp);
            }
        }
        spS[half][j] = sp;
    }
    __syncthreads();

    // ---- scores ----
    const int a0 = (lane & 31) * 8;
    float ss[8], ww[8];
#pragma unroll
    for (int i = 0; i < 8; ++i) {
        ss[i] = spS[0][a0 + i] + spS[1][a0 + i] + bsS[a0 + i];
        ww[i] = wwS[a0 + i];
    }
    const float bw0 = bw[0];
#pragma unroll 2
    for (int p = 0; p < 4; ++p) {
        const int t = w * 8 + p * 2 + (lane >> 5);
        const short8 x8 = *(const short8*)(xProjbf + ((size_t)(b * NT + t)) * NA + a0);
        float s = 0.f;
#pragma unroll
        for (int i = 0; i < 8; ++i)
            s += ww[i] * tanhf(ss[i] + bf2f((unsigned short)x8[i]));
#pragma unroll
        for (int off = 16; off > 0; off >>= 1) s += __shfl_xor(s, off);
        if ((lane & 31) == 0) vS[t] = s + bw0;
    }
    __syncthreads();

    // ---- softmax ----
    if (w == 0) {
        float v = vS[lane];
        float m = v;
#pragma unroll
        for (int off = 32; off > 0; off >>= 1) m = fmaxf(m, __shfl_xor(m, off));
        float e = expf(v - m);
        float ssum = e;
#pragma unroll
        for (int off = 32; off > 0; off >>= 1) ssum += __shfl_xor(ssum, off);
        alphaS[lane] = e / ssum;
    }
    __syncthreads();

    // ---- ctx ----
    const int d0 = lane * 8;
    float c[8];
#pragma unroll
    for (int i = 0; i < 8; ++i) c[i] = 0.f;

    if (use_bf) {
        const unsigned short* ib = imgbf + (size_t)b * NT * ND + d0;
#pragma unroll 2
        for (int i = 0; i < 8; ++i) {
            const int t = w + 8 * i;
            const float al = alphaS[t];
            const short8 v = *(const short8*)(ib + (size_t)t * ND);
#pragma unroll
            for (int k = 0; k < 8; ++k)
                c[k] = fmaf(al, bf2f((unsigned short)v[k]), c[k]);
        }
    } else {
        const float* ib = imgf + (size_t)b * NT * ND + d0;
#pragma unroll 2
        for (int i = 0; i < 8; ++i) {
            const int t = w + 8 * i;
            const float al = alphaS[t];
            const float4 v0 = *(const float4*)(ib + (size_t)t * ND);
            const float4 v1 = *(const float4*)(ib + (size_t)t * ND + 4);
            c[0] = fmaf(al, v0.x, c[0]); c[1] = fmaf(al, v0.y, c[1]);
            c[2] = fmaf(al, v0.z, c[2]); c[3] = fmaf(al, v0.w, c[3]);
            c[4] = fmaf(al, v1.x, c[4]); c[5] = fmaf(al, v1.y, c[5]);
            c[6] = fmaf(al, v1.z, c[6]); c[7] = fmaf(al, v1.w, c[7]);
        }
    }
    *(f32x4*)&ctxS[w][d0] = (f32x4){c[0], c[1], c[2], c[3]};
    *(f32x4*)&ctxS[w][d0 + 4] = (f32x4){c[4], c[5], c[6], c[7]};
    __syncthreads();

    float cx = ctxS[0][tid] + ctxS[1][tid] + ctxS[2][tid] + ctxS[3][tid]
             + ctxS[4][tid] + ctxS[5][tid] + ctxS[6][tid] + ctxS[7][tid];
    Aout[(size_t)b * KGRU + tid] = f2bf(cx);
}

// Final-step FC: out[b,25,:] = h @ Wfc.T + bfc
__global__ __launch_bounds__(128) void k_fc(
    const float* __restrict__ h, const unsigned short* __restrict__ WfcT,
    const float* __restrict__ bfc, float* __restrict__ out)
{
    const int b = blockIdx.x;
    const int j = threadIdx.x;
    __shared__ float hS[NH];
    hS[j] = h[b * NH + j];
    hS[128 + j] = h[b * NH + 128 + j];
    __syncthreads();
    if (j < NC) {
        float acc = bfc[j];
#pragma unroll 8
        for (int k = 0; k < NH; ++k)
            acc = fmaf(hS[k], bf2f(WfcT[k * NC + j]), acc);
        out[((size_t)b * NSTEPS + (NSTEPS - 1)) * NC + j] = acc;
    }
}

// ---------------------------------------------------------------------------
extern "C" void kernel_launch(void* const* d_in, const int* in_sizes, int n_in,
                              void* d_out, int out_size, void* d_ws, size_t ws_size,
                              hipStream_t stream)
{
    const float* img   = (const float*)d_in[0];
    const int*   label = (const int*)d_in[1];
    const float* Wx    = (const float*)d_in[2];
    const float* bx    = (const float*)d_in[3];
    const float* Ws    = (const float*)d_in[4];
    const float* bs    = (const float*)d_in[5];
    const float* Ww    = (const float*)d_in[6];
    const float* bw    = (const float*)d_in[7];
    const float* emb   = (const float*)d_in[8];
    const float* Wih   = (const float*)d_in[9];
    const float* bih   = (const float*)d_in[10];
    const float* Whh   = (const float*)d_in[11];
    const float* bhh   = (const float*)d_in[12];
    const float* Wfc   = (const float*)d_in[13];
    const float* bfc   = (const float*)d_in[14];
    float* out = (float*)d_out;

    float* ws = (float*)d_ws;
    float* h = ws;                                           // 131072 f
    float* P = h + 131072;                                   // 111744 f (97*1152)
    unsigned short* xProjbf = (unsigned short*)(P + 111744); // 8388608 s
    unsigned short* A0   = xProjbf + 8388608;                // 393216 s
    unsigned short* A1   = A0 + 393216;                      // 393216 s
    unsigned short* Wp   = A1 + 393216;                      // 884736 s
    unsigned short* Wxbf = Wp + 884736;                      // 131072 s
    unsigned short* Wsbf = Wxbf + 131072;                    // 65536 s
    unsigned short* WfcT = Wsbf + 65536;                     // 24576 s
    unsigned short* imgbf = WfcT + 24576;                    // 16777216 s (optional)

    const size_t need_bf = (size_t)((char*)(imgbf + 16777216) - (char*)d_ws);
    const int use_bf = (ws_size >= need_bf) ? 1 : 0;

    k_prep<<<dim3(3456), dim3(256), 0, stream>>>(
        Wx, Ws, Wfc, Wih, Whh, Wxbf, Wsbf, WfcT, Wp);

    k_prep2<<<dim3(97, 5), dim3(256), 0, stream>>>(
        emb, Wih, bih, bhh, bfc, P);

    if (use_bf)
        k_convert<<<dim3(8192), dim3(256), 0, stream>>>(img, imgbf);

    k_xproj<<<dim3((NB * NT) / 64, NA / 64), dim3(256), 0, stream>>>(
        img, imgbf, use_bf, Wxbf, bx, xProjbf);

    // init: h=0, A0 = [ctx_0 | 0]
    k_step<<<dim3(NB), dim3(512), 0, stream>>>(
        h, A0, Wsbf, bs, imgbf, img, use_bf, xProjbf, Ww, bw, -1);

    for (int s = 0; s < NSTEPS; ++s) {
        unsigned short* Ain  = (s & 1) ? A1 : A0;
        unsigned short* Aout = (s & 1) ? A0 : A1;

        k_gru<<<dim3(8, 18), dim3(256), 0, stream>>>(
            Ain, Aout, Wp, P, label, h, out, s);

        if (s < NSTEPS - 1)
            k_step<<<dim3(NB), dim3(512), 0, stream>>>(
                h, Aout, Wsbf, bs, imgbf, img, use_bf, xProjbf, Ww, bw, s);
    }

    k_fc<<<dim3(NB), dim3(128), 0, stream>>>(h, WfcT, bfc, out);
}

// Round 7
// 982.637 us; speedup vs baseline: 1.2982x; 1.2982x over previous
//
#include <hip/hip_runtime.h>
#include <math.h>

#define NB 512
#define NT 64
#define ND 512
#define NH 256
#define NA 256
#define NC 96
#define NSTEPS 26
#define NGRU 1152   // 1024 interleaved gru rows + 96 fc + 32 pad
#define KGRU 768    // [ctx(512) | h(256)]

typedef __attribute__((ext_vector_type(8))) short short8;
typedef __attribute__((ext_vector_type(4))) float f32x4;

static __device__ __forceinline__ unsigned short f2bf(float f) {
    unsigned int u = __float_as_uint(f);
    unsigned int r = (u + 0x7FFFu + ((u >> 16) & 1u)) >> 16;
    return (unsigned short)r;
}
static __device__ __forceinline__ float bf2f(unsigned short u) {
    return __uint_as_float(((unsigned int)u) << 16);
}

// ---------------------------------------------------------------------------
// Prep. Wp [1152 x 768] bf16, rows interleaved (4j+g), K = [ctx | h]:
//   g=0 r : [Wih_r[:,256:768] | Whh_r]
//   g=1 z : [Wih_z[:,256:768] | Whh_z]
//   g=2 ni: [Wih_n[:,256:768] | 0    ]
//   g=3 nh: [0                | Whh_n]
//   rows 1024-1119 FC: [0 | Wfc];  1120-1151 pad.
// ---------------------------------------------------------------------------
__global__ __launch_bounds__(256) void k_prep(
    const float* __restrict__ Wx, const float* __restrict__ Ws,
    const float* __restrict__ Wfc, const float* __restrict__ Wih,
    const float* __restrict__ Whh,
    unsigned short* __restrict__ Wxbf, unsigned short* __restrict__ Wsbf,
    unsigned short* __restrict__ WfcT, unsigned short* __restrict__ Wp)
{
    const int idx = blockIdx.x * 256 + threadIdx.x;
    if (idx < NGRU * KGRU) {
        const int n = idx / KGRU, k = idx - n * KGRU;
        float val = 0.f;
        if (n < 1024) {
            const int j = n >> 2, g = n & 3;
            if (k < 512) {
                if (g == 0)      val = Wih[j * 768 + 256 + k];
                else if (g == 1) val = Wih[(256 + j) * 768 + 256 + k];
                else if (g == 2) val = Wih[(512 + j) * 768 + 256 + k];
            } else {
                const int kh = k - 512;
                if (g == 0)      val = Whh[j * 256 + kh];
                else if (g == 1) val = Whh[(256 + j) * 256 + kh];
                else if (g == 3) val = Whh[(512 + j) * 256 + kh];
            }
        } else if (n < 1120) {
            if (k >= 512) val = Wfc[(n - 1024) * 256 + (k - 512)];
        }
        Wp[idx] = f2bf(val);
    }
    if (idx < 131072) Wxbf[idx] = f2bf(Wx[idx]);
    if (idx < 65536)  Wsbf[idx] = f2bf(Ws[idx]);        // row-major [j][k]
    if (idx < 24576) {
        const int k = idx / 96, c = idx % 96;
        WfcT[idx] = f2bf(Wfc[c * 256 + k]);             // WfcT[k][c]
    }
}

// ---------------------------------------------------------------------------
// embProj: P[y][n] = bias(n) + sum_{k<256} emb[y][k] * Wemb(n,k), fp32.
// ---------------------------------------------------------------------------
__global__ __launch_bounds__(256) void k_prep2(
    const float* __restrict__ emb, const float* __restrict__ Wih,
    const float* __restrict__ bih, const float* __restrict__ bhh,
    const float* __restrict__ bfc, float* __restrict__ P)
{
    const int y = blockIdx.x;
    const int n = blockIdx.y * 256 + threadIdx.x;
    __shared__ float embS[256];
    embS[threadIdx.x] = emb[y * 256 + threadIdx.x];
    __syncthreads();
    if (n >= NGRU) return;

    float bias = 0.f;
    const float* src = nullptr;
    if (n < 1024) {
        const int j = n >> 2, g = n & 3;
        if (g == 0)      { bias = bih[j] + bhh[j];             src = Wih + (size_t)j * 768; }
        else if (g == 1) { bias = bih[256 + j] + bhh[256 + j]; src = Wih + (size_t)(256 + j) * 768; }
        else if (g == 2) { bias = bih[512 + j];                src = Wih + (size_t)(512 + j) * 768; }
        else             { bias = bhh[512 + j]; }
    } else if (n < 1120) {
        bias = bfc[n - 1024];
    }
    float sp = bias;
    if (src) {
#pragma unroll 8
        for (int k = 0; k < 256; ++k) sp = fmaf(embS[k], src[k], sp);
    }
    P[(size_t)y * NGRU + n] = sp;
}

// img fp32 -> bf16. grid 8192 x 256.
__global__ __launch_bounds__(256) void k_convert(
    const float* __restrict__ img, unsigned short* __restrict__ imgbf)
{
    const int idx = (blockIdx.x * 256 + threadIdx.x) * 8;
    const float4 v0 = *(const float4*)(img + idx);
    const float4 v1 = *(const float4*)(img + idx + 4);
    short8 o;
    o[0] = (short)f2bf(v0.x); o[1] = (short)f2bf(v0.y);
    o[2] = (short)f2bf(v0.z); o[3] = (short)f2bf(v0.w);
    o[4] = (short)f2bf(v1.x); o[5] = (short)f2bf(v1.y);
    o[6] = (short)f2bf(v1.z); o[7] = (short)f2bf(v1.w);
    *(short8*)(imgbf + idx) = o;
}

// ---------------------------------------------------------------------------
// xProj = img @ Wx.T + bx -> bf16. M=32768 N=256 K=512.
// ---------------------------------------------------------------------------
__global__ __launch_bounds__(256) void k_xproj(
    const float* __restrict__ img, const unsigned short* __restrict__ imgbf,
    int use_bf, const unsigned short* __restrict__ Wxbf,
    const float* __restrict__ bx, unsigned short* __restrict__ xProjbf)
{
    __shared__ unsigned short As[64][40];
    __shared__ unsigned short Bs[64][40];

    const int tid = threadIdx.x;
    const int lane = tid & 63;
    const int w = tid >> 6;
    const int l15 = lane & 15;
    const int q = lane >> 4;
    const int bm = blockIdx.x * 64;
    const int bn = blockIdx.y * 64;
    const int srow = tid >> 2;
    const int sc0 = (tid & 3) * 8;

    f32x4 acc[4];
#pragma unroll
    for (int i = 0; i < 4; ++i) acc[i] = (f32x4){0.f, 0.f, 0.f, 0.f};

    for (int k0 = 0; k0 < ND; k0 += 32) {
        if (use_bf) {
            *(short8*)&As[srow][sc0] =
                *(const short8*)(imgbf + (size_t)(bm + srow) * ND + k0 + sc0);
        } else {
            const float* ap = img + (size_t)(bm + srow) * ND + k0 + sc0;
            const float4 v0 = *(const float4*)ap;
            const float4 v1 = *(const float4*)(ap + 4);
            short8 av;
            av[0] = (short)f2bf(v0.x); av[1] = (short)f2bf(v0.y);
            av[2] = (short)f2bf(v0.z); av[3] = (short)f2bf(v0.w);
            av[4] = (short)f2bf(v1.x); av[5] = (short)f2bf(v1.y);
            av[6] = (short)f2bf(v1.z); av[7] = (short)f2bf(v1.w);
            *(short8*)&As[srow][sc0] = av;
        }
        *(short8*)&Bs[srow][sc0] =
            *(const short8*)(Wxbf + (size_t)(bn + srow) * ND + k0 + sc0);
        __syncthreads();

        const short8 bf = *(const short8*)&Bs[w * 16 + l15][q * 8];
#pragma unroll
        for (int mt = 0; mt < 4; ++mt) {
            const short8 af = *(const short8*)&As[mt * 16 + l15][q * 8];
            acc[mt] = __builtin_amdgcn_mfma_f32_16x16x32_bf16(af, bf, acc[mt], 0, 0, 0);
        }
        __syncthreads();
    }

#pragma unroll
    for (int mt = 0; mt < 4; ++mt) {
        const int col = bn + w * 16 + l15;
        const float bxv = bx[col];
#pragma unroll
        for (int r = 0; r < 4; ++r) {
            const int row = bm + mt * 16 + q * 4 + r;
            xProjbf[(size_t)row * NA + col] = f2bf(acc[mt][r] + bxv);
        }
    }
}

// ---------------------------------------------------------------------------
// GRU GEMM + gate epilogue.  Ain [512,768] = [ctx | h] bf16.
// pre[n] = Ain @ Wp[n].T + P[y_s[b]][n].  32x64 tile, BK=32, grid (16,18).
// ---------------------------------------------------------------------------
__global__ __launch_bounds__(256) void k_gru(
    const unsigned short* __restrict__ Ain, unsigned short* __restrict__ Aout,
    const unsigned short* __restrict__ Wp, const float* __restrict__ P,
    const int* __restrict__ label, float* __restrict__ h,
    float* __restrict__ out, int s)
{
    __shared__ unsigned short As[32][40];
    __shared__ unsigned short Bs[64][40];
    __shared__ float CS[32][65];
    __shared__ int yS[32];

    const int tid = threadIdx.x;
    const int lane = tid & 63;
    const int w = tid >> 6;
    const int l15 = lane & 15;
    const int q = lane >> 4;
    const int bm = blockIdx.x * 32;
    const int bn = blockIdx.y * 64;
    const int srow = tid >> 2;
    const int sc0 = (tid & 3) * 8;

    if (tid < 32)
        yS[tid] = (s == 0) ? 0 : label[(bm + tid) * NSTEPS + s];

    f32x4 acc[2];
    acc[0] = (f32x4){0.f, 0.f, 0.f, 0.f};
    acc[1] = (f32x4){0.f, 0.f, 0.f, 0.f};

    for (int k0 = 0; k0 < KGRU; k0 += 32) {
        *(short8*)&Bs[srow][sc0] =
            *(const short8*)(Wp + (size_t)(bn + srow) * KGRU + k0 + sc0);
        if (tid < 128)
            *(short8*)&As[srow][sc0] =
                *(const short8*)(Ain + (size_t)(bm + srow) * KGRU + k0 + sc0);
        __syncthreads();

        const short8 bf = *(const short8*)&Bs[w * 16 + l15][q * 8];
#pragma unroll
        for (int mt = 0; mt < 2; ++mt) {
            const short8 af = *(const short8*)&As[mt * 16 + l15][q * 8];
            acc[mt] = __builtin_amdgcn_mfma_f32_16x16x32_bf16(af, bf, acc[mt], 0, 0, 0);
        }
        __syncthreads();
    }

    const int col = bn + w * 16 + l15;
    if (blockIdx.y < 16) {
        // gru tile: biased pre-activations to LDS, then gate
#pragma unroll
        for (int mt = 0; mt < 2; ++mt)
#pragma unroll
            for (int r = 0; r < 4; ++r) {
                const int row = mt * 16 + q * 4 + r;
                CS[row][w * 16 + l15] = acc[mt][r] + P[(size_t)yS[row] * NGRU + col];
            }
        __syncthreads();
#pragma unroll
        for (int it = 0; it < 2; ++it) {
            const int u = tid + 256 * it;          // 0..511
            const int row = u >> 4;                // 0..31
            const int jl = u & 15;
            const float r_pre = CS[row][4 * jl + 0];
            const float z_pre = CS[row][4 * jl + 1];
            const float ni    = CS[row][4 * jl + 2];
            const float nh    = CS[row][4 * jl + 3];
            const float r = 1.f / (1.f + expf(-r_pre));
            const float z = 1.f / (1.f + expf(-z_pre));
            const float n = tanhf(fmaf(r, nh, ni));
            const int b = bm + row;
            const int j = (bn >> 2) + jl;
            const float hp = h[b * NH + j];
            const float hn = (1.f - z) * n + z * hp;
            h[b * NH + j] = hn;
            Aout[(size_t)b * KGRU + 512 + j] = f2bf(hn);
        }
    } else {
        if (s >= 1) {
            const int c = col - 1024;
            if (c < NC) {
#pragma unroll
                for (int mt = 0; mt < 2; ++mt)
#pragma unroll
                    for (int r = 0; r < 4; ++r) {
                        const int row = mt * 16 + q * 4 + r;
                        out[((size_t)(bm + row) * NSTEPS + (s - 1)) * NC + c] =
                            acc[mt][r] + P[(size_t)yS[row] * NGRU + col];
                    }
            }
        }
    }
}

// ---------------------------------------------------------------------------
// sProj[512,256] = h_bf16 @ Ws.T + bs.  A = Aout h-slot (offset 512, stride
// 768).  64x64 tile, BK=64, grid (8,4).  init: sProj = bs (h = 0).
// ---------------------------------------------------------------------------
__global__ __launch_bounds__(256) void k_sproj(
    const unsigned short* __restrict__ Ahs, const unsigned short* __restrict__ Wsbf,
    const float* __restrict__ bs, float* __restrict__ sProj, int init)
{
    const int tid = threadIdx.x;
    const int b0 = blockIdx.x * 64;
    const int n0 = blockIdx.y * 64;

    if (init) {
        const int c = tid & 63, rg = tid >> 6;
        const float bv = bs[n0 + c];
#pragma unroll
        for (int i = 0; i < 16; ++i)
            sProj[(size_t)(b0 + rg * 16 + i) * NA + n0 + c] = bv;
        return;
    }

    __shared__ unsigned short As[64][72];
    __shared__ unsigned short Bs[64][72];

    const int lane = tid & 63;
    const int w = tid >> 6;
    const int l15 = lane & 15;
    const int q = lane >> 4;

    f32x4 acc[4];
#pragma unroll
    for (int i = 0; i < 4; ++i) acc[i] = (f32x4){0.f, 0.f, 0.f, 0.f};

    for (int k0 = 0; k0 < NH; k0 += 64) {
#pragma unroll
        for (int rep = 0; rep < 2; ++rep) {
            const int ch = tid + rep * 256;
            const int row = ch >> 3, col8 = (ch & 7) * 8;
            *(short8*)&As[row][col8] =
                *(const short8*)(Ahs + (size_t)(b0 + row) * KGRU + 512 + k0 + col8);
            *(short8*)&Bs[row][col8] =
                *(const short8*)(Wsbf + (size_t)(n0 + row) * NH + k0 + col8);
        }
        __syncthreads();
#pragma unroll
        for (int kk = 0; kk < 64; kk += 32) {
            const short8 bf = *(const short8*)&Bs[w * 16 + l15][kk + q * 8];
#pragma unroll
            for (int mt = 0; mt < 4; ++mt) {
                const short8 af = *(const short8*)&As[mt * 16 + l15][kk + q * 8];
                acc[mt] = __builtin_amdgcn_mfma_f32_16x16x32_bf16(af, bf, acc[mt], 0, 0, 0);
            }
        }
        __syncthreads();
    }

    const int col = n0 + w * 16 + l15;
    const float bv = bs[col];
#pragma unroll
    for (int mt = 0; mt < 4; ++mt)
#pragma unroll
        for (int r = 0; r < 4; ++r)
            sProj[(size_t)(b0 + mt * 16 + q * 4 + r) * NA + col] = acc[mt][r] + bv;
}

// ---------------------------------------------------------------------------
// Attention: scores (sProj precomputed) + softmax + ctx -> Aout[:,0:512].
// 512 threads, grid 512.  step==-1: init (zero h, zero h-slot).
// ---------------------------------------------------------------------------
__global__ __launch_bounds__(512) void k_att(
    float* __restrict__ h, unsigned short* __restrict__ Aout,
    const float* __restrict__ sProj,
    const unsigned short* __restrict__ imgbf, const float* __restrict__ imgf,
    int use_bf, const unsigned short* __restrict__ xProjbf,
    const float* __restrict__ Ww, const float* __restrict__ bw, int step)
{
    const int b = blockIdx.x;
    const int tid = threadIdx.x;
    const int lane = tid & 63;
    const int w = tid >> 6;

    __shared__ float sS[NA];
    __shared__ float wwS[NA];
    __shared__ float vS[NT];
    __shared__ float alphaS[NT];
    __shared__ float ctxS[8][512];

    if (tid < 256) {
        sS[tid] = sProj[b * NA + tid];
        wwS[tid] = Ww[tid];
        if (step < 0) {
            h[b * NH + tid] = 0.f;
            Aout[(size_t)b * KGRU + 512 + tid] = 0;   // bf16(0)
        }
    }
    __syncthreads();

    // ---- scores ----
    const int a0 = (lane & 31) * 8;
    float ss[8], ww[8];
#pragma unroll
    for (int i = 0; i < 8; ++i) {
        ss[i] = sS[a0 + i];
        ww[i] = wwS[a0 + i];
    }
    const float bw0 = bw[0];
#pragma unroll 2
    for (int p = 0; p < 4; ++p) {
        const int t = w * 8 + p * 2 + (lane >> 5);
        const short8 x8 = *(const short8*)(xProjbf + ((size_t)(b * NT + t)) * NA + a0);
        float s = 0.f;
#pragma unroll
        for (int i = 0; i < 8; ++i)
            s += ww[i] * tanhf(ss[i] + bf2f((unsigned short)x8[i]));
#pragma unroll
        for (int off = 16; off > 0; off >>= 1) s += __shfl_xor(s, off);
        if ((lane & 31) == 0) vS[t] = s + bw0;
    }
    __syncthreads();

    // ---- softmax ----
    if (w == 0) {
        float v = vS[lane];
        float m = v;
#pragma unroll
        for (int off = 32; off > 0; off >>= 1) m = fmaxf(m, __shfl_xor(m, off));
        float e = expf(v - m);
        float ssum = e;
#pragma unroll
        for (int off = 32; off > 0; off >>= 1) ssum += __shfl_xor(ssum, off);
        alphaS[lane] = e / ssum;
    }
    __syncthreads();

    // ---- ctx ----
    const int d0 = lane * 8;
    float c[8];
#pragma unroll
    for (int i = 0; i < 8; ++i) c[i] = 0.f;

    if (use_bf) {
        const unsigned short* ib = imgbf + (size_t)b * NT * ND + d0;
#pragma unroll 2
        for (int i = 0; i < 8; ++i) {
            const int t = w + 8 * i;
            const float al = alphaS[t];
            const short8 v = *(const short8*)(ib + (size_t)t * ND);
#pragma unroll
            for (int k = 0; k < 8; ++k)
                c[k] = fmaf(al, bf2f((unsigned short)v[k]), c[k]);
        }
    } else {
        const float* ib = imgf + (size_t)b * NT * ND + d0;
#pragma unroll 2
        for (int i = 0; i < 8; ++i) {
            const int t = w + 8 * i;
            const float al = alphaS[t];
            const float4 v0 = *(const float4*)(ib + (size_t)t * ND);
            const float4 v1 = *(const float4*)(ib + (size_t)t * ND + 4);
            c[0] = fmaf(al, v0.x, c[0]); c[1] = fmaf(al, v0.y, c[1]);
            c[2] = fmaf(al, v0.z, c[2]); c[3] = fmaf(al, v0.w, c[3]);
            c[4] = fmaf(al, v1.x, c[4]); c[5] = fmaf(al, v1.y, c[5]);
            c[6] = fmaf(al, v1.z, c[6]); c[7] = fmaf(al, v1.w, c[7]);
        }
    }
    *(f32x4*)&ctxS[w][d0] = (f32x4){c[0], c[1], c[2], c[3]};
    *(f32x4*)&ctxS[w][d0 + 4] = (f32x4){c[4], c[5], c[6], c[7]};
    __syncthreads();

    float cx = ctxS[0][tid] + ctxS[1][tid] + ctxS[2][tid] + ctxS[3][tid]
             + ctxS[4][tid] + ctxS[5][tid] + ctxS[6][tid] + ctxS[7][tid];
    Aout[(size_t)b * KGRU + tid] = f2bf(cx);
}

// Final-step FC: out[b,25,:] = h @ Wfc.T + bfc
__global__ __launch_bounds__(128) void k_fc(
    const float* __restrict__ h, const unsigned short* __restrict__ WfcT,
    const float* __restrict__ bfc, float* __restrict__ out)
{
    const int b = blockIdx.x;
    const int j = threadIdx.x;
    __shared__ float hS[NH];
    hS[j] = h[b * NH + j];
    hS[128 + j] = h[b * NH + 128 + j];
    __syncthreads();
    if (j < NC) {
        float acc = bfc[j];
#pragma unroll 8
        for (int k = 0; k < NH; ++k)
            acc = fmaf(hS[k], bf2f(WfcT[k * NC + j]), acc);
        out[((size_t)b * NSTEPS + (NSTEPS - 1)) * NC + j] = acc;
    }
}

// ---------------------------------------------------------------------------
extern "C" void kernel_launch(void* const* d_in, const int* in_sizes, int n_in,
                              void* d_out, int out_size, void* d_ws, size_t ws_size,
                              hipStream_t stream)
{
    const float* img   = (const float*)d_in[0];
    const int*   label = (const int*)d_in[1];
    const float* Wx    = (const float*)d_in[2];
    const float* bx    = (const float*)d_in[3];
    const float* Ws    = (const float*)d_in[4];
    const float* bs    = (const float*)d_in[5];
    const float* Ww    = (const float*)d_in[6];
    const float* bw    = (const float*)d_in[7];
    const float* emb   = (const float*)d_in[8];
    const float* Wih   = (const float*)d_in[9];
    const float* bih   = (const float*)d_in[10];
    const float* Whh   = (const float*)d_in[11];
    const float* bhh   = (const float*)d_in[12];
    const float* Wfc   = (const float*)d_in[13];
    const float* bfc   = (const float*)d_in[14];
    float* out = (float*)d_out;

    float* ws = (float*)d_ws;
    float* h     = ws;                                       // 131072 f
    float* sProj = h + 131072;                               // 131072 f
    float* P     = sProj + 131072;                           // 111744 f (97*1152)
    unsigned short* xProjbf = (unsigned short*)(P + 111744); // 8388608 s
    unsigned short* A0   = xProjbf + 8388608;                // 393216 s
    unsigned short* A1   = A0 + 393216;                      // 393216 s
    unsigned short* Wp   = A1 + 393216;                      // 884736 s
    unsigned short* Wxbf = Wp + 884736;                      // 131072 s
    unsigned short* Wsbf = Wxbf + 131072;                    // 65536 s
    unsigned short* WfcT = Wsbf + 65536;                     // 24576 s
    unsigned short* imgbf = WfcT + 24576;                    // 16777216 s (optional)

    const size_t need_bf = (size_t)((char*)(imgbf + 16777216) - (char*)d_ws);
    const int use_bf = (ws_size >= need_bf) ? 1 : 0;

    k_prep<<<dim3(3456), dim3(256), 0, stream>>>(
        Wx, Ws, Wfc, Wih, Whh, Wxbf, Wsbf, WfcT, Wp);

    k_prep2<<<dim3(97, 5), dim3(256), 0, stream>>>(
        emb, Wih, bih, bhh, bfc, P);

    if (use_bf)
        k_convert<<<dim3(8192), dim3(256), 0, stream>>>(img, imgbf);

    k_xproj<<<dim3((NB * NT) / 64, NA / 64), dim3(256), 0, stream>>>(
        img, imgbf, use_bf, Wxbf, bx, xProjbf);

    // init: sProj_0 = bs; k_att(-1): h=0, A0 = [ctx_0 | 0]
    k_sproj<<<dim3(8, 4), dim3(256), 0, stream>>>(A0, Wsbf, bs, sProj, 1);
    k_att<<<dim3(NB), dim3(512), 0, stream>>>(
        h, A0, sProj, imgbf, img, use_bf, xProjbf, Ww, bw, -1);

    for (int s = 0; s < NSTEPS; ++s) {
        unsigned short* Ain  = (s & 1) ? A1 : A0;
        unsigned short* Aout = (s & 1) ? A0 : A1;

        k_gru<<<dim3(16, 18), dim3(256), 0, stream>>>(
            Ain, Aout, Wp, P, label, h, out, s);

        if (s < NSTEPS - 1) {
            k_sproj<<<dim3(8, 4), dim3(256), 0, stream>>>(Aout, Wsbf, bs, sProj, 0);
            k_att<<<dim3(NB), dim3(512), 0, stream>>>(
                h, Aout, sProj, imgbf, img, use_bf, xProjbf, Ww, bw, s);
        }
    }

    k_fc<<<dim3(NB), dim3(128), 0, stream>>>(h, WfcT, bfc, out);
}

// Round 8
// 836.601 us; speedup vs baseline: 1.5248x; 1.1746x over previous
//
#include <hip/hip_runtime.h>
#include <math.h>

#define NB 512
#define NT 64
#define ND 512
#define NH 256
#define NA 256
#define NC 96
#define NSTEPS 26
#define NGRU 1152   // 1024 interleaved gru rows + 96 fc + 32 pad
#define KGRU 768    // [ctx(512) | h(256)]

typedef __attribute__((ext_vector_type(8))) short short8;
typedef __attribute__((ext_vector_type(4))) float f32x4;

static __device__ __forceinline__ unsigned short f2bf(float f) {
    unsigned int u = __float_as_uint(f);
    unsigned int r = (u + 0x7FFFu + ((u >> 16) & 1u)) >> 16;
    return (unsigned short)r;
}
static __device__ __forceinline__ float bf2f(unsigned short u) {
    return __uint_as_float(((unsigned int)u) << 16);
}

// ---------------------------------------------------------------------------
// Prep. Wp [1152 x 768] bf16, rows interleaved (4j+g), K = [ctx | h].
// ---------------------------------------------------------------------------
__global__ __launch_bounds__(256) void k_prep(
    const float* __restrict__ Wx, const float* __restrict__ Ws,
    const float* __restrict__ Wfc, const float* __restrict__ Wih,
    const float* __restrict__ Whh,
    unsigned short* __restrict__ Wxbf, unsigned short* __restrict__ Wsbf,
    unsigned short* __restrict__ WfcT, unsigned short* __restrict__ Wp)
{
    const int idx = blockIdx.x * 256 + threadIdx.x;
    if (idx < NGRU * KGRU) {
        const int n = idx / KGRU, k = idx - n * KGRU;
        float val = 0.f;
        if (n < 1024) {
            const int j = n >> 2, g = n & 3;
            if (k < 512) {
                if (g == 0)      val = Wih[j * 768 + 256 + k];
                else if (g == 1) val = Wih[(256 + j) * 768 + 256 + k];
                else if (g == 2) val = Wih[(512 + j) * 768 + 256 + k];
            } else {
                const int kh = k - 512;
                if (g == 0)      val = Whh[j * 256 + kh];
                else if (g == 1) val = Whh[(256 + j) * 256 + kh];
                else if (g == 3) val = Whh[(512 + j) * 256 + kh];
            }
        } else if (n < 1120) {
            if (k >= 512) val = Wfc[(n - 1024) * 256 + (k - 512)];
        }
        Wp[idx] = f2bf(val);
    }
    if (idx < 131072) Wxbf[idx] = f2bf(Wx[idx]);
    if (idx < 65536)  Wsbf[idx] = f2bf(Ws[idx]);        // row-major [j][k]
    if (idx < 24576) {
        const int k = idx / 96, c = idx % 96;
        WfcT[idx] = f2bf(Wfc[c * 256 + k]);             // WfcT[k][c]
    }
}

// ---------------------------------------------------------------------------
// embProj: P[y][n] = bias(n) + sum_{k<256} emb[y][k] * Wemb(n,k), fp32.
// ---------------------------------------------------------------------------
__global__ __launch_bounds__(256) void k_prep2(
    const float* __restrict__ emb, const float* __restrict__ Wih,
    const float* __restrict__ bih, const float* __restrict__ bhh,
    const float* __restrict__ bfc, float* __restrict__ P)
{
    const int y = blockIdx.x;
    const int n = blockIdx.y * 256 + threadIdx.x;
    __shared__ float embS[256];
    embS[threadIdx.x] = emb[y * 256 + threadIdx.x];
    __syncthreads();
    if (n >= NGRU) return;

    float bias = 0.f;
    const float* src = nullptr;
    if (n < 1024) {
        const int j = n >> 2, g = n & 3;
        if (g == 0)      { bias = bih[j] + bhh[j];             src = Wih + (size_t)j * 768; }
        else if (g == 1) { bias = bih[256 + j] + bhh[256 + j]; src = Wih + (size_t)(256 + j) * 768; }
        else if (g == 2) { bias = bih[512 + j];                src = Wih + (size_t)(512 + j) * 768; }
        else             { bias = bhh[512 + j]; }
    } else if (n < 1120) {
        bias = bfc[n - 1024];
    }
    float sp = bias;
    if (src) {
#pragma unroll 8
        for (int k = 0; k < 256; ++k) sp = fmaf(embS[k], src[k], sp);
    }
    P[(size_t)y * NGRU + n] = sp;
}

// img fp32 -> bf16. grid 8192 x 256.
__global__ __launch_bounds__(256) void k_convert(
    const float* __restrict__ img, unsigned short* __restrict__ imgbf)
{
    const int idx = (blockIdx.x * 256 + threadIdx.x) * 8;
    const float4 v0 = *(const float4*)(img + idx);
    const float4 v1 = *(const float4*)(img + idx + 4);
    short8 o;
    o[0] = (short)f2bf(v0.x); o[1] = (short)f2bf(v0.y);
    o[2] = (short)f2bf(v0.z); o[3] = (short)f2bf(v0.w);
    o[4] = (short)f2bf(v1.x); o[5] = (short)f2bf(v1.y);
    o[6] = (short)f2bf(v1.z); o[7] = (short)f2bf(v1.w);
    *(short8*)(imgbf + idx) = o;
}

// ---------------------------------------------------------------------------
// xProj = img @ Wx.T + bx -> bf16. M=32768 N=256 K=512.
// ---------------------------------------------------------------------------
__global__ __launch_bounds__(256) void k_xproj(
    const float* __restrict__ img, const unsigned short* __restrict__ imgbf,
    int use_bf, const unsigned short* __restrict__ Wxbf,
    const float* __restrict__ bx, unsigned short* __restrict__ xProjbf)
{
    __shared__ unsigned short As[64][40];
    __shared__ unsigned short Bs[64][40];

    const int tid = threadIdx.x;
    const int lane = tid & 63;
    const int w = tid >> 6;
    const int l15 = lane & 15;
    const int q = lane >> 4;
    const int bm = blockIdx.x * 64;
    const int bn = blockIdx.y * 64;
    const int srow = tid >> 2;
    const int sc0 = (tid & 3) * 8;

    f32x4 acc[4];
#pragma unroll
    for (int i = 0; i < 4; ++i) acc[i] = (f32x4){0.f, 0.f, 0.f, 0.f};

    for (int k0 = 0; k0 < ND; k0 += 32) {
        if (use_bf) {
            *(short8*)&As[srow][sc0] =
                *(const short8*)(imgbf + (size_t)(bm + srow) * ND + k0 + sc0);
        } else {
            const float* ap = img + (size_t)(bm + srow) * ND + k0 + sc0;
            const float4 v0 = *(const float4*)ap;
            const float4 v1 = *(const float4*)(ap + 4);
            short8 av;
            av[0] = (short)f2bf(v0.x); av[1] = (short)f2bf(v0.y);
            av[2] = (short)f2bf(v0.z); av[3] = (short)f2bf(v0.w);
            av[4] = (short)f2bf(v1.x); av[5] = (short)f2bf(v1.y);
            av[6] = (short)f2bf(v1.z); av[7] = (short)f2bf(v1.w);
            *(short8*)&As[srow][sc0] = av;
        }
        *(short8*)&Bs[srow][sc0] =
            *(const short8*)(Wxbf + (size_t)(bn + srow) * ND + k0 + sc0);
        __syncthreads();

        const short8 bf = *(const short8*)&Bs[w * 16 + l15][q * 8];
#pragma unroll
        for (int mt = 0; mt < 4; ++mt) {
            const short8 af = *(const short8*)&As[mt * 16 + l15][q * 8];
            acc[mt] = __builtin_amdgcn_mfma_f32_16x16x32_bf16(af, bf, acc[mt], 0, 0, 0);
        }
        __syncthreads();
    }

#pragma unroll
    for (int mt = 0; mt < 4; ++mt) {
        const int col = bn + w * 16 + l15;
        const float bxv = bx[col];
#pragma unroll
        for (int r = 0; r < 4; ++r) {
            const int row = bm + mt * 16 + q * 4 + r;
            xProjbf[(size_t)row * NA + col] = f2bf(acc[mt][r] + bxv);
        }
    }
}

// ---------------------------------------------------------------------------
// GRU GEMM + gate epilogue.  16x64 tile, 128 threads, grid (32,18)=576.
// A strip (16x768) preloaded to LDS once; K-loop stages only B, BK=64.
// ---------------------------------------------------------------------------
__global__ __launch_bounds__(128) void k_gru(
    const unsigned short* __restrict__ Ain, unsigned short* __restrict__ Aout,
    const unsigned short* __restrict__ Wp, const float* __restrict__ P,
    const int* __restrict__ label, float* __restrict__ h,
    float* __restrict__ out, int s)
{
    __shared__ unsigned short Af[16][776];     // 768 + 8 pad
    __shared__ unsigned short Bs[64][72];      // 64  + 8 pad
    __shared__ float CS[16][65];
    __shared__ int yS[16];

    const int tid = threadIdx.x;       // 0..127
    const int lane = tid & 63;
    const int w = tid >> 6;            // 0..1
    const int l15 = lane & 15;
    const int q = lane >> 4;
    const int bm = blockIdx.x * 16;
    const int bn = blockIdx.y * 64;

    if (tid < 16) yS[tid] = (s == 0) ? 0 : label[(bm + tid) * NSTEPS + s];

    // preload A strip: 16 rows x 768 shorts = 1536 chunks of 8 shorts
#pragma unroll
    for (int i = 0; i < 12; ++i) {
        const int c = tid + 128 * i;
        const int row = c / 96;
        const int col8 = (c - row * 96) * 8;
        *(short8*)&Af[row][col8] =
            *(const short8*)(Ain + (size_t)(bm + row) * KGRU + col8);
    }

    f32x4 acc[2];
    acc[0] = (f32x4){0.f, 0.f, 0.f, 0.f};
    acc[1] = (f32x4){0.f, 0.f, 0.f, 0.f};

    for (int k0 = 0; k0 < KGRU; k0 += 64) {
        // stage B tile: 64 rows x 64 shorts = 512 chunks
#pragma unroll
        for (int i = 0; i < 4; ++i) {
            const int c = tid + 128 * i;
            const int row = c >> 3, col8 = (c & 7) * 8;
            *(short8*)&Bs[row][col8] =
                *(const short8*)(Wp + (size_t)(bn + row) * KGRU + k0 + col8);
        }
        __syncthreads();
#pragma unroll
        for (int kk = 0; kk < 64; kk += 32) {
            const short8 af = *(const short8*)&Af[l15][k0 + kk + q * 8];
#pragma unroll
            for (int nt = 0; nt < 2; ++nt) {
                const short8 bf = *(const short8*)&Bs[(w * 2 + nt) * 16 + l15][kk + q * 8];
                acc[nt] = __builtin_amdgcn_mfma_f32_16x16x32_bf16(af, bf, acc[nt], 0, 0, 0);
            }
        }
        __syncthreads();
    }

    if (blockIdx.y < 16) {
        // gru tile: biased pre-activations to LDS, then gate
#pragma unroll
        for (int nt = 0; nt < 2; ++nt) {
            const int cl = (w * 2 + nt) * 16 + l15;
            const float pv0 = P[(size_t)yS[q * 4 + 0] * NGRU + bn + cl];
            const float pv1 = P[(size_t)yS[q * 4 + 1] * NGRU + bn + cl];
            const float pv2 = P[(size_t)yS[q * 4 + 2] * NGRU + bn + cl];
            const float pv3 = P[(size_t)yS[q * 4 + 3] * NGRU + bn + cl];
            CS[q * 4 + 0][cl] = acc[nt][0] + pv0;
            CS[q * 4 + 1][cl] = acc[nt][1] + pv1;
            CS[q * 4 + 2][cl] = acc[nt][2] + pv2;
            CS[q * 4 + 3][cl] = acc[nt][3] + pv3;
        }
        __syncthreads();
#pragma unroll
        for (int it = 0; it < 2; ++it) {
            const int u = tid + 128 * it;          // 0..255
            const int row = u >> 4;                // 0..15
            const int jl = u & 15;
            const float r_pre = CS[row][4 * jl + 0];
            const float z_pre = CS[row][4 * jl + 1];
            const float ni    = CS[row][4 * jl + 2];
            const float nh    = CS[row][4 * jl + 3];
            const float r = 1.f / (1.f + expf(-r_pre));
            const float z = 1.f / (1.f + expf(-z_pre));
            const float n = tanhf(fmaf(r, nh, ni));
            const int b = bm + row;
            const int j = (bn >> 2) + jl;
            const float hp = h[b * NH + j];
            const float hn = (1.f - z) * n + z * hp;
            h[b * NH + j] = hn;
            Aout[(size_t)b * KGRU + 512 + j] = f2bf(hn);
        }
    } else {
        if (s >= 1) {
#pragma unroll
            for (int nt = 0; nt < 2; ++nt) {
                const int col = bn + (w * 2 + nt) * 16 + l15;
                const int c = col - 1024;
                if (c < NC) {
#pragma unroll
                    for (int r = 0; r < 4; ++r) {
                        const int row = q * 4 + r;
                        out[((size_t)(bm + row) * NSTEPS + (s - 1)) * NC + c] =
                            acc[nt][r] + P[(size_t)yS[row] * NGRU + col];
                    }
                }
            }
        }
    }
}

// ---------------------------------------------------------------------------
// sProj[512,256] = h_bf16 @ Ws.T + bs.  A = Aout h-slot (offset 512, stride
// 768).  64x64 tile, BK=64, grid (8,4).  init: sProj = bs (h = 0).
// ---------------------------------------------------------------------------
__global__ __launch_bounds__(256) void k_sproj(
    const unsigned short* __restrict__ Ahs, const unsigned short* __restrict__ Wsbf,
    const float* __restrict__ bs, float* __restrict__ sProj, int init)
{
    const int tid = threadIdx.x;
    const int b0 = blockIdx.x * 64;
    const int n0 = blockIdx.y * 64;

    if (init) {
        const int c = tid & 63, rg = tid >> 6;
        const float bv = bs[n0 + c];
#pragma unroll
        for (int i = 0; i < 16; ++i)
            sProj[(size_t)(b0 + rg * 16 + i) * NA + n0 + c] = bv;
        return;
    }

    __shared__ unsigned short As[64][72];
    __shared__ unsigned short Bs[64][72];

    const int lane = tid & 63;
    const int w = tid >> 6;
    const int l15 = lane & 15;
    const int q = lane >> 4;

    f32x4 acc[4];
#pragma unroll
    for (int i = 0; i < 4; ++i) acc[i] = (f32x4){0.f, 0.f, 0.f, 0.f};

    for (int k0 = 0; k0 < NH; k0 += 64) {
#pragma unroll
        for (int rep = 0; rep < 2; ++rep) {
            const int ch = tid + rep * 256;
            const int row = ch >> 3, col8 = (ch & 7) * 8;
            *(short8*)&As[row][col8] =
                *(const short8*)(Ahs + (size_t)(b0 + row) * KGRU + 512 + k0 + col8);
            *(short8*)&Bs[row][col8] =
                *(const short8*)(Wsbf + (size_t)(n0 + row) * NH + k0 + col8);
        }
        __syncthreads();
#pragma unroll
        for (int kk = 0; kk < 64; kk += 32) {
            const short8 bf = *(const short8*)&Bs[w * 16 + l15][kk + q * 8];
#pragma unroll
            for (int mt = 0; mt < 4; ++mt) {
                const short8 af = *(const short8*)&As[mt * 16 + l15][kk + q * 8];
                acc[mt] = __builtin_amdgcn_mfma_f32_16x16x32_bf16(af, bf, acc[mt], 0, 0, 0);
            }
        }
        __syncthreads();
    }

    const int col = n0 + w * 16 + l15;
    const float bv = bs[col];
#pragma unroll
    for (int mt = 0; mt < 4; ++mt)
#pragma unroll
        for (int r = 0; r < 4; ++r)
            sProj[(size_t)(b0 + mt * 16 + q * 4 + r) * NA + col] = acc[mt][r] + bv;
}

// ---------------------------------------------------------------------------
// Attention: scores (sProj precomputed) + softmax + ctx -> Aout[:,0:512].
// 512 threads, grid 512.  step==-1: init (zero h, zero h-slot).
// ---------------------------------------------------------------------------
__global__ __launch_bounds__(512) void k_att(
    float* __restrict__ h, unsigned short* __restrict__ Aout,
    const float* __restrict__ sProj,
    const unsigned short* __restrict__ imgbf, const float* __restrict__ imgf,
    int use_bf, const unsigned short* __restrict__ xProjbf,
    const float* __restrict__ Ww, const float* __restrict__ bw, int step)
{
    const int b = blockIdx.x;
    const int tid = threadIdx.x;
    const int lane = tid & 63;
    const int w = tid >> 6;

    __shared__ float sS[NA];
    __shared__ float wwS[NA];
    __shared__ float vS[NT];
    __shared__ float alphaS[NT];
    __shared__ float ctxS[8][512];

    if (tid < 256) {
        sS[tid] = sProj[b * NA + tid];
        wwS[tid] = Ww[tid];
        if (step < 0) {
            h[b * NH + tid] = 0.f;
            Aout[(size_t)b * KGRU + 512 + tid] = 0;   // bf16(0)
        }
    }
    __syncthreads();

    // ---- scores ----
    const int a0 = (lane & 31) * 8;
    float ss[8], ww[8];
#pragma unroll
    for (int i = 0; i < 8; ++i) {
        ss[i] = sS[a0 + i];
        ww[i] = wwS[a0 + i];
    }
    const float bw0 = bw[0];
#pragma unroll 2
    for (int p = 0; p < 4; ++p) {
        const int t = w * 8 + p * 2 + (lane >> 5);
        const short8 x8 = *(const short8*)(xProjbf + ((size_t)(b * NT + t)) * NA + a0);
        float s = 0.f;
#pragma unroll
        for (int i = 0; i < 8; ++i)
            s += ww[i] * tanhf(ss[i] + bf2f((unsigned short)x8[i]));
#pragma unroll
        for (int off = 16; off > 0; off >>= 1) s += __shfl_xor(s, off);
        if ((lane & 31) == 0) vS[t] = s + bw0;
    }
    __syncthreads();

    // ---- softmax ----
    if (w == 0) {
        float v = vS[lane];
        float m = v;
#pragma unroll
        for (int off = 32; off > 0; off >>= 1) m = fmaxf(m, __shfl_xor(m, off));
        float e = expf(v - m);
        float ssum = e;
#pragma unroll
        for (int off = 32; off > 0; off >>= 1) ssum += __shfl_xor(ssum, off);
        alphaS[lane] = e / ssum;
    }
    __syncthreads();

    // ---- ctx ----
    const int d0 = lane * 8;
    float c[8];
#pragma unroll
    for (int i = 0; i < 8; ++i) c[i] = 0.f;

    if (use_bf) {
        const unsigned short* ib = imgbf + (size_t)b * NT * ND + d0;
#pragma unroll 2
        for (int i = 0; i < 8; ++i) {
            const int t = w + 8 * i;
            const float al = alphaS[t];
            const short8 v = *(const short8*)(ib + (size_t)t * ND);
#pragma unroll
            for (int k = 0; k < 8; ++k)
                c[k] = fmaf(al, bf2f((unsigned short)v[k]), c[k]);
        }
    } else {
        const float* ib = imgf + (size_t)b * NT * ND + d0;
#pragma unroll 2
        for (int i = 0; i < 8; ++i) {
            const int t = w + 8 * i;
            const float al = alphaS[t];
            const float4 v0 = *(const float4*)(ib + (size_t)t * ND);
            const float4 v1 = *(const float4*)(ib + (size_t)t * ND + 4);
            c[0] = fmaf(al, v0.x, c[0]); c[1] = fmaf(al, v0.y, c[1]);
            c[2] = fmaf(al, v0.z, c[2]); c[3] = fmaf(al, v0.w, c[3]);
            c[4] = fmaf(al, v1.x, c[4]); c[5] = fmaf(al, v1.y, c[5]);
            c[6] = fmaf(al, v1.z, c[6]); c[7] = fmaf(al, v1.w, c[7]);
        }
    }
    *(f32x4*)&ctxS[w][d0] = (f32x4){c[0], c[1], c[2], c[3]};
    *(f32x4*)&ctxS[w][d0 + 4] = (f32x4){c[4], c[5], c[6], c[7]};
    __syncthreads();

    float cx = ctxS[0][tid] + ctxS[1][tid] + ctxS[2][tid] + ctxS[3][tid]
             + ctxS[4][tid] + ctxS[5][tid] + ctxS[6][tid] + ctxS[7][tid];
    Aout[(size_t)b * KGRU + tid] = f2bf(cx);
}

// Final-step FC: out[b,25,:] = h @ Wfc.T + bfc
__global__ __launch_bounds__(128) void k_fc(
    const float* __restrict__ h, const unsigned short* __restrict__ WfcT,
    const float* __restrict__ bfc, float* __restrict__ out)
{
    const int b = blockIdx.x;
    const int j = threadIdx.x;
    __shared__ float hS[NH];
    hS[j] = h[b * NH + j];
    hS[128 + j] = h[b * NH + 128 + j];
    __syncthreads();
    if (j < NC) {
        float acc = bfc[j];
#pragma unroll 8
        for (int k = 0; k < NH; ++k)
            acc = fmaf(hS[k], bf2f(WfcT[k * NC + j]), acc);
        out[((size_t)b * NSTEPS + (NSTEPS - 1)) * NC + j] = acc;
    }
}

// ---------------------------------------------------------------------------
extern "C" void kernel_launch(void* const* d_in, const int* in_sizes, int n_in,
                              void* d_out, int out_size, void* d_ws, size_t ws_size,
                              hipStream_t stream)
{
    const float* img   = (const float*)d_in[0];
    const int*   label = (const int*)d_in[1];
    const float* Wx    = (const float*)d_in[2];
    const float* bx    = (const float*)d_in[3];
    const float* Ws    = (const float*)d_in[4];
    const float* bs    = (const float*)d_in[5];
    const float* Ww    = (const float*)d_in[6];
    const float* bw    = (const float*)d_in[7];
    const float* emb   = (const float*)d_in[8];
    const float* Wih   = (const float*)d_in[9];
    const float* bih   = (const float*)d_in[10];
    const float* Whh   = (const float*)d_in[11];
    const float* bhh   = (const float*)d_in[12];
    const float* Wfc   = (const float*)d_in[13];
    const float* bfc   = (const float*)d_in[14];
    float* out = (float*)d_out;

    float* ws = (float*)d_ws;
    float* h     = ws;                                       // 131072 f
    float* sProj = h + 131072;                               // 131072 f
    float* P     = sProj + 131072;                           // 111744 f (97*1152)
    unsigned short* xProjbf = (unsigned short*)(P + 111744); // 8388608 s
    unsigned short* A0   = xProjbf + 8388608;                // 393216 s
    unsigned short* A1   = A0 + 393216;                      // 393216 s
    unsigned short* Wp   = A1 + 393216;                      // 884736 s
    unsigned short* Wxbf = Wp + 884736;                      // 131072 s
    unsigned short* Wsbf = Wxbf + 131072;                    // 65536 s
    unsigned short* WfcT = Wsbf + 65536;                     // 24576 s
    unsigned short* imgbf = WfcT + 24576;                    // 16777216 s (optional)

    const size_t need_bf = (size_t)((char*)(imgbf + 16777216) - (char*)d_ws);
    const int use_bf = (ws_size >= need_bf) ? 1 : 0;

    k_prep<<<dim3(3456), dim3(256), 0, stream>>>(
        Wx, Ws, Wfc, Wih, Whh, Wxbf, Wsbf, WfcT, Wp);

    k_prep2<<<dim3(97, 5), dim3(256), 0, stream>>>(
        emb, Wih, bih, bhh, bfc, P);

    if (use_bf)
        k_convert<<<dim3(8192), dim3(256), 0, stream>>>(img, imgbf);

    k_xproj<<<dim3((NB * NT) / 64, NA / 64), dim3(256), 0, stream>>>(
        img, imgbf, use_bf, Wxbf, bx, xProjbf);

    // init: sProj_0 = bs; k_att(-1): h=0, A0 = [ctx_0 | 0]
    k_sproj<<<dim3(8, 4), dim3(256), 0, stream>>>(A0, Wsbf, bs, sProj, 1);
    k_att<<<dim3(NB), dim3(512), 0, stream>>>(
        h, A0, sProj, imgbf, img, use_bf, xProjbf, Ww, bw, -1);

    for (int s = 0; s < NSTEPS; ++s) {
        unsigned short* Ain  = (s & 1) ? A1 : A0;
        unsigned short* Aout = (s & 1) ? A0 : A1;

        k_gru<<<dim3(32, 18), dim3(128), 0, stream>>>(
            Ain, Aout, Wp, P, label, h, out, s);

        if (s < NSTEPS - 1) {
            k_sproj<<<dim3(8, 4), dim3(256), 0, stream>>>(Aout, Wsbf, bs, sProj, 0);
            k_att<<<dim3(NB), dim3(512), 0, stream>>>(
                h, Aout, sProj, imgbf, img, use_bf, xProjbf, Ww, bw, s);
        }
    }

    k_fc<<<dim3(NB), dim3(128), 0, stream>>>(h, WfcT, bfc, out);
}

// Round 9
// 817.340 us; speedup vs baseline: 1.5607x; 1.0236x over previous
//
#include <hip/hip_runtime.h>
#include <math.h>

#define NB 512
#define NT 64
#define ND 512
#define NH 256
#define NA 256
#define NC 96
#define NSTEPS 26
#define NGRU 1152   // 1024 interleaved gru rows + 96 fc + 32 pad
#define KGRU 768    // [ctx(512) | h(256)]

typedef __attribute__((ext_vector_type(8))) short short8;
typedef __attribute__((ext_vector_type(4))) float f32x4;

static __device__ __forceinline__ unsigned short f2bf(float f) {
    unsigned int u = __float_as_uint(f);
    unsigned int r = (u + 0x7FFFu + ((u >> 16) & 1u)) >> 16;
    return (unsigned short)r;
}
static __device__ __forceinline__ float bf2f(unsigned short u) {
    return __uint_as_float(((unsigned int)u) << 16);
}
// fast tanh/sigmoid via v_exp_f32 (args here are small; asymptotes safe)
static __device__ __forceinline__ float ftanh(float x) {
    const float e = __expf(2.0f * x);
    return 1.0f - 2.0f / (e + 1.0f);
}
static __device__ __forceinline__ float fsigm(float x) {
    return 1.0f / (1.0f + __expf(-x));
}

// ---------------------------------------------------------------------------
// Prep. Wp [1152 x 768] bf16 interleaved (4j+g), K = [ctx | h]; plus
// Wxbf, Wsbf, WfcT, embbf[128x256] (pad rows zero), WihE[1152x256] bf16
// (emb-K part of the interleaved rows), biasv[1152] fp32.
// grid 3456 x 256 (covers 884736 = NGRU*KGRU, the largest array).
// ---------------------------------------------------------------------------
__global__ __launch_bounds__(256) void k_prep(
    const float* __restrict__ Wx, const float* __restrict__ Ws,
    const float* __restrict__ Wfc, const float* __restrict__ Wih,
    const float* __restrict__ Whh, const float* __restrict__ emb,
    const float* __restrict__ bih, const float* __restrict__ bhh,
    const float* __restrict__ bfc,
    unsigned short* __restrict__ Wxbf, unsigned short* __restrict__ Wsbf,
    unsigned short* __restrict__ WfcT, unsigned short* __restrict__ Wp,
    unsigned short* __restrict__ embbf, unsigned short* __restrict__ WihE,
    float* __restrict__ biasv)
{
    const int idx = blockIdx.x * 256 + threadIdx.x;
    if (idx < NGRU * KGRU) {
        const int n = idx / KGRU, k = idx - n * KGRU;
        float val = 0.f;
        if (n < 1024) {
            const int j = n >> 2, g = n & 3;
            if (k < 512) {
                if (g == 0)      val = Wih[j * 768 + 256 + k];
                else if (g == 1) val = Wih[(256 + j) * 768 + 256 + k];
                else if (g == 2) val = Wih[(512 + j) * 768 + 256 + k];
            } else {
                const int kh = k - 512;
                if (g == 0)      val = Whh[j * 256 + kh];
                else if (g == 1) val = Whh[(256 + j) * 256 + kh];
                else if (g == 3) val = Whh[(512 + j) * 256 + kh];
            }
        } else if (n < 1120) {
            if (k >= 512) val = Wfc[(n - 1024) * 256 + (k - 512)];
        }
        Wp[idx] = f2bf(val);
    }
    if (idx < 294912) {                              // WihE [1152][256]
        const int n = idx >> 8, k = idx & 255;
        float val = 0.f;
        if (n < 1024) {
            const int j = n >> 2, g = n & 3;
            if (g == 0)      val = Wih[j * 768 + k];
            else if (g == 1) val = Wih[(256 + j) * 768 + k];
            else if (g == 2) val = Wih[(512 + j) * 768 + k];
        }
        WihE[idx] = f2bf(val);
    }
    if (idx < 131072) Wxbf[idx] = f2bf(Wx[idx]);
    if (idx < 65536)  Wsbf[idx] = f2bf(Ws[idx]);     // row-major [j][k]
    if (idx < 32768) {                               // embbf [128][256]
        const int y = idx >> 8;
        embbf[idx] = (y < 97) ? f2bf(emb[idx]) : 0;
    }
    if (idx < 24576) {
        const int k = idx / 96, c = idx % 96;
        WfcT[idx] = f2bf(Wfc[c * 256 + k]);          // WfcT[k][c]
    }
    if (idx < NGRU) {
        float v = 0.f;
        if (idx < 1024) {
            const int j = idx >> 2, g = idx & 3;
            if (g == 0)      v = bih[j] + bhh[j];
            else if (g == 1) v = bih[256 + j] + bhh[256 + j];
            else if (g == 2) v = bih[512 + j];
            else             v = bhh[512 + j];
        } else if (idx < 1120) {
            v = bfc[idx - 1024];
        }
        biasv[idx] = v;
    }
}

// ---------------------------------------------------------------------------
// P[97,1152] = embbf[128,256] @ WihE[1152,256].T + biasv  (MFMA, fp32 out)
// 64x64 tile, BK=64, grid (2,18).
// ---------------------------------------------------------------------------
__global__ __launch_bounds__(256) void k_pemb(
    const unsigned short* __restrict__ embbf, const unsigned short* __restrict__ WihE,
    const float* __restrict__ biasv, float* __restrict__ P)
{
    __shared__ unsigned short As[64][72];
    __shared__ unsigned short Bs[64][72];

    const int tid = threadIdx.x;
    const int lane = tid & 63;
    const int w = tid >> 6;
    const int l15 = lane & 15;
    const int q = lane >> 4;
    const int b0 = blockIdx.x * 64;
    const int n0 = blockIdx.y * 64;

    f32x4 acc[4];
#pragma unroll
    for (int i = 0; i < 4; ++i) acc[i] = (f32x4){0.f, 0.f, 0.f, 0.f};

    for (int k0 = 0; k0 < 256; k0 += 64) {
#pragma unroll
        for (int rep = 0; rep < 2; ++rep) {
            const int ch = tid + rep * 256;
            const int row = ch >> 3, col8 = (ch & 7) * 8;
            *(short8*)&As[row][col8] =
                *(const short8*)(embbf + (size_t)(b0 + row) * 256 + k0 + col8);
            *(short8*)&Bs[row][col8] =
                *(const short8*)(WihE + (size_t)(n0 + row) * 256 + k0 + col8);
        }
        __syncthreads();
#pragma unroll
        for (int kk = 0; kk < 64; kk += 32) {
            const short8 bf = *(const short8*)&Bs[w * 16 + l15][kk + q * 8];
#pragma unroll
            for (int mt = 0; mt < 4; ++mt) {
                const short8 af = *(const short8*)&As[mt * 16 + l15][kk + q * 8];
                acc[mt] = __builtin_amdgcn_mfma_f32_16x16x32_bf16(af, bf, acc[mt], 0, 0, 0);
            }
        }
        __syncthreads();
    }

    const int col = n0 + w * 16 + l15;
    const float bv = biasv[col];
#pragma unroll
    for (int mt = 0; mt < 4; ++mt)
#pragma unroll
        for (int r = 0; r < 4; ++r) {
            const int y = b0 + mt * 16 + q * 4 + r;
            if (y < 97) P[(size_t)y * NGRU + col] = acc[mt][r] + bv;
        }
}

// img fp32 -> bf16. grid 8192 x 256.
__global__ __launch_bounds__(256) void k_convert(
    const float* __restrict__ img, unsigned short* __restrict__ imgbf)
{
    const int idx = (blockIdx.x * 256 + threadIdx.x) * 8;
    const float4 v0 = *(const float4*)(img + idx);
    const float4 v1 = *(const float4*)(img + idx + 4);
    short8 o;
    o[0] = (short)f2bf(v0.x); o[1] = (short)f2bf(v0.y);
    o[2] = (short)f2bf(v0.z); o[3] = (short)f2bf(v0.w);
    o[4] = (short)f2bf(v1.x); o[5] = (short)f2bf(v1.y);
    o[6] = (short)f2bf(v1.z); o[7] = (short)f2bf(v1.w);
    *(short8*)(imgbf + idx) = o;
}

// ---------------------------------------------------------------------------
// xProj = img @ Wx.T + bx -> bf16. M=32768 N=256 K=512. 64x64 tile, BK=64,
// double-buffered staging. grid (512,4).
// ---------------------------------------------------------------------------
__global__ __launch_bounds__(256) void k_xproj(
    const float* __restrict__ img, const unsigned short* __restrict__ imgbf,
    int use_bf, const unsigned short* __restrict__ Wxbf,
    const float* __restrict__ bx, unsigned short* __restrict__ xProjbf)
{
    __shared__ unsigned short As[2][64][72];
    __shared__ unsigned short Bs[2][64][72];

    const int tid = threadIdx.x;
    const int lane = tid & 63;
    const int w = tid >> 6;
    const int l15 = lane & 15;
    const int q = lane >> 4;
    const int bm = blockIdx.x * 64;
    const int bn = blockIdx.y * 64;
    const int row0 = tid >> 3, col80 = (tid & 7) * 8;       // rep 0
    const int row1 = (tid + 256) >> 3, col81 = col80;       // rep 1

    f32x4 acc[4];
#pragma unroll
    for (int i = 0; i < 4; ++i) acc[i] = (f32x4){0.f, 0.f, 0.f, 0.f};

    // load A chunk (8 bf16) at (row, k0+col8)
    auto loadA = [&](int row, int col8, int k0) -> short8 {
        if (use_bf)
            return *(const short8*)(imgbf + (size_t)(bm + row) * ND + k0 + col8);
        const float* ap = img + (size_t)(bm + row) * ND + k0 + col8;
        const float4 v0 = *(const float4*)ap;
        const float4 v1 = *(const float4*)(ap + 4);
        short8 av;
        av[0] = (short)f2bf(v0.x); av[1] = (short)f2bf(v0.y);
        av[2] = (short)f2bf(v0.z); av[3] = (short)f2bf(v0.w);
        av[4] = (short)f2bf(v1.x); av[5] = (short)f2bf(v1.y);
        av[6] = (short)f2bf(v1.z); av[7] = (short)f2bf(v1.w);
        return av;
    };

    // preload round 0
    *(short8*)&As[0][row0][col80] = loadA(row0, col80, 0);
    *(short8*)&As[0][row1][col81] = loadA(row1, col81, 0);
    *(short8*)&Bs[0][row0][col80] = *(const short8*)(Wxbf + (size_t)(bn + row0) * ND + col80);
    *(short8*)&Bs[0][row1][col81] = *(const short8*)(Wxbf + (size_t)(bn + row1) * ND + col81);
    __syncthreads();

    for (int it = 0; it < 8; ++it) {
        const int cur = it & 1;
        short8 na0, na1, nb0, nb1;
        if (it < 7) {
            const int k0n = (it + 1) * 64;
            na0 = loadA(row0, col80, k0n);
            na1 = loadA(row1, col81, k0n);
            nb0 = *(const short8*)(Wxbf + (size_t)(bn + row0) * ND + k0n + col80);
            nb1 = *(const short8*)(Wxbf + (size_t)(bn + row1) * ND + k0n + col81);
        }
#pragma unroll
        for (int kk = 0; kk < 64; kk += 32) {
            const short8 bf = *(const short8*)&Bs[cur][w * 16 + l15][kk + q * 8];
#pragma unroll
            for (int mt = 0; mt < 4; ++mt) {
                const short8 af = *(const short8*)&As[cur][mt * 16 + l15][kk + q * 8];
                acc[mt] = __builtin_amdgcn_mfma_f32_16x16x32_bf16(af, bf, acc[mt], 0, 0, 0);
            }
        }
        if (it < 7) {
            *(short8*)&As[cur ^ 1][row0][col80] = na0;
            *(short8*)&As[cur ^ 1][row1][col81] = na1;
            *(short8*)&Bs[cur ^ 1][row0][col80] = nb0;
            *(short8*)&Bs[cur ^ 1][row1][col81] = nb1;
        }
        __syncthreads();
    }

#pragma unroll
    for (int mt = 0; mt < 4; ++mt) {
        const int col = bn + w * 16 + l15;
        const float bxv = bx[col];
#pragma unroll
        for (int r = 0; r < 4; ++r) {
            const int row = bm + mt * 16 + q * 4 + r;
            xProjbf[(size_t)row * NA + col] = f2bf(acc[mt][r] + bxv);
        }
    }
}

// ---------------------------------------------------------------------------
// GRU GEMM + gate epilogue.  16x64 tile, 128 threads, grid (32,18)=576.
// A strip (16x768) LDS-resident; B double-buffered, BK=64 (12 rounds).
// ---------------------------------------------------------------------------
__global__ __launch_bounds__(128) void k_gru(
    const unsigned short* __restrict__ Ain, unsigned short* __restrict__ Aout,
    const unsigned short* __restrict__ Wp, const float* __restrict__ P,
    const int* __restrict__ label, float* __restrict__ h,
    float* __restrict__ out, int s)
{
    __shared__ unsigned short Af[16][776];     // 768 + 8 pad
    __shared__ unsigned short Bs[2][64][72];
    __shared__ float CS[16][65];
    __shared__ int yS[16];

    const int tid = threadIdx.x;       // 0..127
    const int lane = tid & 63;
    const int w = tid >> 6;            // 0..1
    const int l15 = lane & 15;
    const int q = lane >> 4;
    const int bm = blockIdx.x * 16;
    const int bn = blockIdx.y * 64;

    if (tid < 16) yS[tid] = (s == 0) ? 0 : label[(bm + tid) * NSTEPS + s];

    // preload A strip: 16 rows x 768 shorts = 1536 chunks of 8
#pragma unroll
    for (int i = 0; i < 12; ++i) {
        const int c = tid + 128 * i;
        const int row = c / 96;
        const int col8 = (c - row * 96) * 8;
        *(short8*)&Af[row][col8] =
            *(const short8*)(Ain + (size_t)(bm + row) * KGRU + col8);
    }
    // preload B round 0: 64x64 shorts = 512 chunks, 4/thread
#pragma unroll
    for (int i = 0; i < 4; ++i) {
        const int c = tid + 128 * i;
        const int row = c >> 3, col8 = (c & 7) * 8;
        *(short8*)&Bs[0][row][col8] =
            *(const short8*)(Wp + (size_t)(bn + row) * KGRU + col8);
    }

    f32x4 acc[2];
    acc[0] = (f32x4){0.f, 0.f, 0.f, 0.f};
    acc[1] = (f32x4){0.f, 0.f, 0.f, 0.f};
    __syncthreads();

    for (int it = 0; it < 12; ++it) {
        const int cur = it & 1;
        short8 nb[4];
        if (it < 11) {
            const int k0n = (it + 1) * 64;
#pragma unroll
            for (int i = 0; i < 4; ++i) {
                const int c = tid + 128 * i;
                const int row = c >> 3, col8 = (c & 7) * 8;
                nb[i] = *(const short8*)(Wp + (size_t)(bn + row) * KGRU + k0n + col8);
            }
        }
        const int k0 = it * 64;
#pragma unroll
        for (int kk = 0; kk < 64; kk += 32) {
            const short8 af = *(const short8*)&Af[l15][k0 + kk + q * 8];
#pragma unroll
            for (int nt = 0; nt < 2; ++nt) {
                const short8 bf = *(const short8*)&Bs[cur][(w * 2 + nt) * 16 + l15][kk + q * 8];
                acc[nt] = __builtin_amdgcn_mfma_f32_16x16x32_bf16(af, bf, acc[nt], 0, 0, 0);
            }
        }
        if (it < 11) {
#pragma unroll
            for (int i = 0; i < 4; ++i) {
                const int c = tid + 128 * i;
                const int row = c >> 3, col8 = (c & 7) * 8;
                *(short8*)&Bs[cur ^ 1][row][col8] = nb[i];
            }
        }
        __syncthreads();
    }

    if (blockIdx.y < 16) {
        // gru tile: biased pre-activations to LDS, then gate
#pragma unroll
        for (int nt = 0; nt < 2; ++nt) {
            const int cl = (w * 2 + nt) * 16 + l15;
#pragma unroll
            for (int r = 0; r < 4; ++r)
                CS[q * 4 + r][cl] = acc[nt][r] + P[(size_t)yS[q * 4 + r] * NGRU + bn + cl];
        }
        __syncthreads();
#pragma unroll
        for (int it = 0; it < 2; ++it) {
            const int u = tid + 128 * it;          // 0..255
            const int row = u >> 4;                // 0..15
            const int jl = u & 15;
            const float r_pre = CS[row][4 * jl + 0];
            const float z_pre = CS[row][4 * jl + 1];
            const float ni    = CS[row][4 * jl + 2];
            const float nh    = CS[row][4 * jl + 3];
            const float r = fsigm(r_pre);
            const float z = fsigm(z_pre);
            const float n = ftanh(fmaf(r, nh, ni));
            const int b = bm + row;
            const int j = (bn >> 2) + jl;
            const float hp = h[b * NH + j];
            const float hn = (1.f - z) * n + z * hp;
            h[b * NH + j] = hn;
            Aout[(size_t)b * KGRU + 512 + j] = f2bf(hn);
        }
    } else {
        if (s >= 1) {
#pragma unroll
            for (int nt = 0; nt < 2; ++nt) {
                const int col = bn + (w * 2 + nt) * 16 + l15;
                const int c = col - 1024;
                if (c < NC) {
#pragma unroll
                    for (int r = 0; r < 4; ++r) {
                        const int row = q * 4 + r;
                        out[((size_t)(bm + row) * NSTEPS + (s - 1)) * NC + c] =
                            acc[nt][r] + P[(size_t)yS[row] * NGRU + col];
                    }
                }
            }
        }
    }
}

// ---------------------------------------------------------------------------
// sProj[512,256] = h_bf16 @ Ws.T + bs.  A = Aout h-slot (offset 512, stride
// 768).  64x64 tile, BK=64, grid (8,4).  init: sProj = bs (h = 0).
// ---------------------------------------------------------------------------
__global__ __launch_bounds__(256) void k_sproj(
    const unsigned short* __restrict__ Ahs, const unsigned short* __restrict__ Wsbf,
    const float* __restrict__ bs, float* __restrict__ sProj, int init)
{
    const int tid = threadIdx.x;
    const int b0 = blockIdx.x * 64;
    const int n0 = blockIdx.y * 64;

    if (init) {
        const int c = tid & 63, rg = tid >> 6;
        const float bv = bs[n0 + c];
#pragma unroll
        for (int i = 0; i < 16; ++i)
            sProj[(size_t)(b0 + rg * 16 + i) * NA + n0 + c] = bv;
        return;
    }

    __shared__ unsigned short As[64][72];
    __shared__ unsigned short Bs[64][72];

    const int lane = tid & 63;
    const int w = tid >> 6;
    const int l15 = lane & 15;
    const int q = lane >> 4;

    f32x4 acc[4];
#pragma unroll
    for (int i = 0; i < 4; ++i) acc[i] = (f32x4){0.f, 0.f, 0.f, 0.f};

    for (int k0 = 0; k0 < NH; k0 += 64) {
#pragma unroll
        for (int rep = 0; rep < 2; ++rep) {
            const int ch = tid + rep * 256;
            const int row = ch >> 3, col8 = (ch & 7) * 8;
            *(short8*)&As[row][col8] =
                *(const short8*)(Ahs + (size_t)(b0 + row) * KGRU + 512 + k0 + col8);
            *(short8*)&Bs[row][col8] =
                *(const short8*)(Wsbf + (size_t)(n0 + row) * NH + k0 + col8);
        }
        __syncthreads();
#pragma unroll
        for (int kk = 0; kk < 64; kk += 32) {
            const short8 bf = *(const short8*)&Bs[w * 16 + l15][kk + q * 8];
#pragma unroll
            for (int mt = 0; mt < 4; ++mt) {
                const short8 af = *(const short8*)&As[mt * 16 + l15][kk + q * 8];
                acc[mt] = __builtin_amdgcn_mfma_f32_16x16x32_bf16(af, bf, acc[mt], 0, 0, 0);
            }
        }
        __syncthreads();
    }

    const int col = n0 + w * 16 + l15;
    const float bv = bs[col];
#pragma unroll
    for (int mt = 0; mt < 4; ++mt)
#pragma unroll
        for (int r = 0; r < 4; ++r)
            sProj[(size_t)(b0 + mt * 16 + q * 4 + r) * NA + col] = acc[mt][r] + bv;
}

// ---------------------------------------------------------------------------
// Attention: scores (sProj precomputed) + softmax + ctx -> Aout[:,0:512].
// 512 threads, grid 512.  step==-1: init (zero h, zero h-slot).
// ---------------------------------------------------------------------------
__global__ __launch_bounds__(512) void k_att(
    float* __restrict__ h, unsigned short* __restrict__ Aout,
    const float* __restrict__ sProj,
    const unsigned short* __restrict__ imgbf, const float* __restrict__ imgf,
    int use_bf, const unsigned short* __restrict__ xProjbf,
    const float* __restrict__ Ww, const float* __restrict__ bw, int step)
{
    const int b = blockIdx.x;
    const int tid = threadIdx.x;
    const int lane = tid & 63;
    const int w = tid >> 6;

    __shared__ float sS[NA];
    __shared__ float wwS[NA];
    __shared__ float vS[NT];
    __shared__ float alphaS[NT];
    __shared__ float ctxS[8][512];

    if (tid < 256) {
        sS[tid] = sProj[b * NA + tid];
        wwS[tid] = Ww[tid];
        if (step < 0) {
            h[b * NH + tid] = 0.f;
            Aout[(size_t)b * KGRU + 512 + tid] = 0;   // bf16(0)
        }
    }
    __syncthreads();

    // ---- scores ----
    const int a0 = (lane & 31) * 8;
    float ss[8], ww[8];
#pragma unroll
    for (int i = 0; i < 8; ++i) {
        ss[i] = sS[a0 + i];
        ww[i] = wwS[a0 + i];
    }
    const float bw0 = bw[0];
#pragma unroll 2
    for (int p = 0; p < 4; ++p) {
        const int t = w * 8 + p * 2 + (lane >> 5);
        const short8 x8 = *(const short8*)(xProjbf + ((size_t)(b * NT + t)) * NA + a0);
        float s = 0.f;
#pragma unroll
        for (int i = 0; i < 8; ++i)
            s += ww[i] * ftanh(ss[i] + bf2f((unsigned short)x8[i]));
#pragma unroll
        for (int off = 16; off > 0; off >>= 1) s += __shfl_xor(s, off);
        if ((lane & 31) == 0) vS[t] = s + bw0;
    }
    __syncthreads();

    // ---- softmax ----
    if (w == 0) {
        float v = vS[lane];
        float m = v;
#pragma unroll
        for (int off = 32; off > 0; off >>= 1) m = fmaxf(m, __shfl_xor(m, off));
        float e = __expf(v - m);
        float ssum = e;
#pragma unroll
        for (int off = 32; off > 0; off >>= 1) ssum += __shfl_xor(ssum, off);
        alphaS[lane] = e / ssum;
    }
    __syncthreads();

    // ---- ctx ----
    const int d0 = lane * 8;
    float c[8];
#pragma unroll
    for (int i = 0; i < 8; ++i) c[i] = 0.f;

    if (use_bf) {
        const unsigned short* ib = imgbf + (size_t)b * NT * ND + d0;
#pragma unroll 2
        for (int i = 0; i < 8; ++i) {
            const int t = w + 8 * i;
            const float al = alphaS[t];
            const short8 v = *(const short8*)(ib + (size_t)t * ND);
#pragma unroll
            for (int k = 0; k < 8; ++k)
                c[k] = fmaf(al, bf2f((unsigned short)v[k]), c[k]);
        }
    } else {
        const float* ib = imgf + (size_t)b * NT * ND + d0;
#pragma unroll 2
        for (int i = 0; i < 8; ++i) {
            const int t = w + 8 * i;
            const float al = alphaS[t];
            const float4 v0 = *(const float4*)(ib + (size_t)t * ND);
            const float4 v1 = *(const float4*)(ib + (size_t)t * ND + 4);
            c[0] = fmaf(al, v0.x, c[0]); c[1] = fmaf(al, v0.y, c[1]);
            c[2] = fmaf(al, v0.z, c[2]); c[3] = fmaf(al, v0.w, c[3]);
            c[4] = fmaf(al, v1.x, c[4]); c[5] = fmaf(al, v1.y, c[5]);
            c[6] = fmaf(al, v1.z, c[6]); c[7] = fmaf(al, v1.w, c[7]);
        }
    }
    *(f32x4*)&ctxS[w][d0] = (f32x4){c[0], c[1], c[2], c[3]};
    *(f32x4*)&ctxS[w][d0 + 4] = (f32x4){c[4], c[5], c[6], c[7]};
    __syncthreads();

    float cx = ctxS[0][tid] + ctxS[1][tid] + ctxS[2][tid] + ctxS[3][tid]
             + ctxS[4][tid] + ctxS[5][tid] + ctxS[6][tid] + ctxS[7][tid];
    Aout[(size_t)b * KGRU + tid] = f2bf(cx);
}

// Final-step FC: out[b,25,:] = h @ Wfc.T + bfc
__global__ __launch_bounds__(128) void k_fc(
    const float* __restrict__ h, const unsigned short* __restrict__ WfcT,
    const float* __restrict__ bfc, float* __restrict__ out)
{
    const int b = blockIdx.x;
    const int j = threadIdx.x;
    __shared__ float hS[NH];
    hS[j] = h[b * NH + j];
    hS[128 + j] = h[b * NH + 128 + j];
    __syncthreads();
    if (j < NC) {
        float acc = bfc[j];
#pragma unroll 8
        for (int k = 0; k < NH; ++k)
            acc = fmaf(hS[k], bf2f(WfcT[k * NC + j]), acc);
        out[((size_t)b * NSTEPS + (NSTEPS - 1)) * NC + j] = acc;
    }
}

// ---------------------------------------------------------------------------
extern "C" void kernel_launch(void* const* d_in, const int* in_sizes, int n_in,
                              void* d_out, int out_size, void* d_ws, size_t ws_size,
                              hipStream_t stream)
{
    const float* img   = (const float*)d_in[0];
    const int*   label = (const int*)d_in[1];
    const float* Wx    = (const float*)d_in[2];
    const float* bx    = (const float*)d_in[3];
    const float* Ws    = (const float*)d_in[4];
    const float* bs    = (const float*)d_in[5];
    const float* Ww    = (const float*)d_in[6];
    const float* bw    = (const float*)d_in[7];
    const float* emb   = (const float*)d_in[8];
    const float* Wih   = (const float*)d_in[9];
    const float* bih   = (const float*)d_in[10];
    const float* Whh   = (const float*)d_in[11];
    const float* bhh   = (const float*)d_in[12];
    const float* Wfc   = (const float*)d_in[13];
    const float* bfc   = (const float*)d_in[14];
    float* out = (float*)d_out;

    float* ws = (float*)d_ws;
    float* h     = ws;                                       // 131072 f
    float* sProj = h + 131072;                               // 131072 f
    float* P     = sProj + 131072;                           // 111744 f (97*1152)
    float* biasv = P + 111744;                               // 1152 f (+pad)
    unsigned short* xProjbf = (unsigned short*)(biasv + 1280);  // 8388608 s
    unsigned short* A0    = xProjbf + 8388608;               // 393216 s
    unsigned short* A1    = A0 + 393216;                     // 393216 s
    unsigned short* Wp    = A1 + 393216;                     // 884736 s
    unsigned short* Wxbf  = Wp + 884736;                     // 131072 s
    unsigned short* Wsbf  = Wxbf + 131072;                   // 65536 s
    unsigned short* WfcT  = Wsbf + 65536;                    // 24576 s
    unsigned short* embbf = WfcT + 24576;                    // 32768 s
    unsigned short* WihE  = embbf + 32768;                   // 294912 s
    unsigned short* imgbf = WihE + 294912;                   // 16777216 s (optional)

    const size_t need_bf = (size_t)((char*)(imgbf + 16777216) - (char*)d_ws);
    const int use_bf = (ws_size >= need_bf) ? 1 : 0;

    k_prep<<<dim3(3456), dim3(256), 0, stream>>>(
        Wx, Ws, Wfc, Wih, Whh, emb, bih, bhh, bfc,
        Wxbf, Wsbf, WfcT, Wp, embbf, WihE, biasv);

    k_pemb<<<dim3(2, 18), dim3(256), 0, stream>>>(embbf, WihE, biasv, P);

    if (use_bf)
        k_convert<<<dim3(8192), dim3(256), 0, stream>>>(img, imgbf);

    k_xproj<<<dim3((NB * NT) / 64, NA / 64), dim3(256), 0, stream>>>(
        img, imgbf, use_bf, Wxbf, bx, xProjbf);

    // init: sProj_0 = bs; k_att(-1): h=0, A0 = [ctx_0 | 0]
    k_sproj<<<dim3(8, 4), dim3(256), 0, stream>>>(A0, Wsbf, bs, sProj, 1);
    k_att<<<dim3(NB), dim3(512), 0, stream>>>(
        h, A0, sProj, imgbf, img, use_bf, xProjbf, Ww, bw, -1);

    for (int s = 0; s < NSTEPS; ++s) {
        unsigned short* Ain  = (s & 1) ? A1 : A0;
        unsigned short* Aout = (s & 1) ? A0 : A1;

        k_gru<<<dim3(32, 18), dim3(128), 0, stream>>>(
            Ain, Aout, Wp, P, label, h, out, s);

        if (s < NSTEPS - 1) {
            k_sproj<<<dim3(8, 4), dim3(256), 0, stream>>>(Aout, Wsbf, bs, sProj, 0);
            k_att<<<dim3(NB), dim3(512), 0, stream>>>(
                h, Aout, sProj, imgbf, img, use_bf, xProjbf, Ww, bw, s);
        }
    }

    k_fc<<<dim3(NB), dim3(128), 0, stream>>>(h, WfcT, bfc, out);
}